// Round 11
// baseline (365.475 us; speedup 1.0000x reference)
//
#include <hip/hip_runtime.h>

#define BSZ   32768
#define H     512
#define K1DIM 532      // H + 20
#define KPAD  544      // padded to multiple of 32 (ws path)
#define ASTR  552      // LDS A row stride in shorts (2-way bank aliasing only)
#define BM    128      // rows per block (R7 evidence: BM=64/2-blocks regressed timed +8.7%)
#define CD    1024
#define NCATS 262144
#define LNEPS 1e-6f

typedef short bf16x8 __attribute__((ext_vector_type(8)));   // 8 bf16 in 4 VGPRs
typedef float f32x4  __attribute__((ext_vector_type(4)));

__device__ __forceinline__ unsigned short f2bf(float x) {
    unsigned int u = __float_as_uint(x);
    u += 0x7FFFu + ((u >> 16) & 1u);        // RNE
    return (unsigned short)(u >> 16);
}

__device__ __forceinline__ unsigned int pack_bf2(float lo, float hi) {
    return __builtin_amdgcn_perm(__float_as_uint(hi), __float_as_uint(lo), 0x07060302u);
}

// sum over 16 contiguous lanes via DPP only; full sum valid on ln==15 (R6-verified)
__device__ __forceinline__ float dpp_red16(float x) {
    x += __int_as_float(__builtin_amdgcn_update_dpp(0, __float_as_int(x), 0xB1, 0xf, 0xf, true)); // quad_perm [1,0,3,2]
    x += __int_as_float(__builtin_amdgcn_update_dpp(0, __float_as_int(x), 0x4E, 0xf, 0xf, true)); // quad_perm [2,3,0,1]
    x += __int_as_float(__builtin_amdgcn_update_dpp(0, __float_as_int(x), 0x114, 0xf, 0xf, true)); // row_shr:4
    x += __int_as_float(__builtin_amdgcn_update_dpp(0, __float_as_int(x), 0x118, 0xf, 0xf, true)); // row_shr:8
    return x;
}

// p-ary lower_bound over sorted cat_seg: 3 rounds of 64 probes (one wave) — R6-verified
__device__ __forceinline__ int psearch64(const int* __restrict__ seg, int target) {
    int lane = threadIdx.x & 63;
    int lo = 0, step = 4096;
    #pragma unroll
    for (int lvl = 0; lvl < 3; ++lvl) {
        int idx = lo + lane * step;
        bool lt = (idx < NCATS) && (seg[idx < NCATS ? idx : NCATS - 1] < target);
        unsigned long long m = __ballot(lt);
        int c = __popcll(m);
        if (c > 0) lo = lo + (c - 1) * step + 1;
        step >>= 6;
    }
    return lo;
}

// ---------- merged prep: w1 fold+convert | G/B0 columns | c0/c1 ----------
// R8: ends with a device-scope release fence (writeback dirty L2) so the ws
// handoff to k_mainw survives GRAPH REPLAY, where the driver's implicit
// inter-node cache maintenance is elided (R2 failure mechanism).
__global__ void k_prep(const float* __restrict__ w1f, const float* __restrict__ ln1_g,
                       const float* __restrict__ ln1_b, const float* __restrict__ ln2_g,
                       const float* __restrict__ ln2_b, const float* __restrict__ out_w,
                       const float* __restrict__ out_b,
                       unsigned short* __restrict__ w1b, float* __restrict__ G,
                       float* __restrict__ B0, float* __restrict__ c0, float* __restrict__ c1) {
    const int bid = blockIdx.x, tid = threadIdx.x;
    if (bid < 2176) {
        int idx = bid * 256 + tid;                      // covers CD*KPAD exactly
        int row = idx / KPAD, k = idx - row * KPAD;
        float v = (k < K1DIM) ? w1f[(size_t)row * K1DIM + k] * ln1_g[k] : 0.f;  // fold ln1_g
        w1b[idx] = f2bf(v);
    } else if (bid < 2432) {
        int col = (bid - 2176) * 4 + (tid >> 6);
        int lane = tid & 63;
        float g = 0.f, b = 0.f;
        for (int k = lane; k < K1DIM; k += 64) {
            float wv = w1f[(size_t)col * K1DIM + k];
            g = fmaf(ln1_g[k], wv, g);
            b = fmaf(ln1_b[k], wv, b);
        }
        for (int m = 1; m < 64; m <<= 1) { g += __shfl_xor(g, m); b += __shfl_xor(b, m); }
        if (lane == 0) { G[col] = g; B0[col] = b; }
    } else {
        int j = tid >> 5, lane = tid & 31;
        if (j < 6) {
            float s1 = 0.f, s0 = 0.f;
            for (int c = lane; c < CD; c += 32) {
                float w = out_w[j * CD + c];
                s1 = fmaf(ln2_g[c], w, s1);
                s0 = fmaf(ln2_b[c], w, s0);
            }
            for (int m = 1; m < 32; m <<= 1) { s1 += __shfl_xor(s1, m); s0 += __shfl_xor(s0, m); }
            if (lane == 0) { c1[j] = s1; c0[j] = s0 + out_b[j]; }
        }
    }
    __threadfence();     // RELEASE: write back this thread's ws stores to L3/HBM
}

// ================= ws-path fused kernel: BM=128, 1 block/CU, 2 waves/SIMD =================
// R8: entry acquire fence (invalidate stale L2 lines before ws reads). At kernel
// entry nothing is cached yet per block, so the invalidate is ~free — unlike the
// R4-R6 spin design whose mid-kernel fence nuked a hot L2 before the GEMM (~60 us).
__global__ __launch_bounds__(512, 2) void k_mainw(
    const float* __restrict__ encode, const float* __restrict__ credit,
    const float* __restrict__ meta_table, const float* __restrict__ conv_w,
    const float* __restrict__ conv_b,
    const unsigned short* __restrict__ w1b, const float* __restrict__ b1,
    const float* __restrict__ ln2_g, const float* __restrict__ out_w,
    const float* __restrict__ Gc, const float* __restrict__ B0c,
    const float* __restrict__ c0p, const float* __restrict__ c1p,
    const int* __restrict__ meta_ids, const int* __restrict__ cat_ids,
    const int* __restrict__ cat_seg, float* __restrict__ out)
{
    __shared__ unsigned short Alds[BM * ASTR];   // 141312 B (raw bf16 x; ln1_g folded into W)
    __shared__ float Ssum[BM][10];               // 5120 B  [row][s,q,p0..5,pad,pad] — atomic acc
    __shared__ float cwL[90], cbL[5];
    __shared__ float sEnc[BM], qEnc[BM];         // stats, then overwritten with mu/rs
    __shared__ float mu2[BM], rs2[BM];
    __shared__ float c0L[6], c1L[6];
    __shared__ int   startsL[BM + 1];
    __shared__ int   sLoL, sHiL;

    __threadfence();     // ACQUIRE: discard stale L2 lines (graph replay elides driver inv)

    const int tid  = threadIdx.x;
    const int row0 = blockIdx.x * BM;
    const int lane = tid & 63;
    const int w    = tid >> 6;

    // ---- Phase A: p-ary boundary searches (waves 0,1) || constants (rest) + zero Ssum
    if (w == 0) {
        int L = psearch64(cat_seg, row0);
        if (lane == 0) sLoL = L;
    } else if (w == 1) {
        int L = psearch64(cat_seg, row0 + BM);
        if (lane == 0) sHiL = L;
    } else {
        const int t = tid - 128;
        if (t < 90) cwL[t] = conv_w[t];
        else if (t < 95) cbL[t - 90] = conv_b[t - 90];
        else if (t < 101) c0L[t - 95] = c0p[t - 95];
        else if (t < 107) c1L[t - 101] = c1p[t - 101];
    }
    for (int i = tid; i < BM * 10; i += 512) ((float*)Ssum)[i] = 0.f;
    __syncthreads();

    // ---- Phase B: boundary scan + encode staging/stats (two 64-row halves, 8 lanes/row)
    {
        const int slo = sLoL, shi = sHiL;
        for (int i = slo - 1 + tid; i < shi; i += 512) {
            int a = (i >= 0) ? cat_seg[i] : -1;
            int b = (i + 1 < NCATS) ? cat_seg[i + 1] : BSZ;
            int rlo = max(a + 1, row0);
            int rhi = min(b, row0 + BM);
            for (int r = rlo; r <= rhi; ++r) startsL[r - row0] = i + 1;
        }
    }
    #pragma unroll
    for (int rr = 0; rr < 2; ++rr) {
        const int r  = (tid >> 3) + rr * 64;
        const int cl = tid & 7;
        const float* erow = encode + (size_t)(row0 + r) * H;
        unsigned short* arow = Alds + r * ASTR;
        float s = 0.f, q = 0.f;
        #pragma unroll 4
        for (int i = 0; i < 16; i++) {
            int col = cl * 4 + i * 32;
            const float4 v = *(const float4*)(erow + col);
            s += v.x + v.y + v.z + v.w;
            q += v.x*v.x + v.y*v.y + v.z*v.z + v.w*v.w;
            ushort4 st = { f2bf(v.x), f2bf(v.y), f2bf(v.z), f2bf(v.w) };
            *(ushort4*)(arow + col) = st;
        }
        #pragma unroll
        for (int m = 1; m <= 4; m <<= 1) { s += __shfl_xor(s, m); q += __shfl_xor(q, m); }
        if (cl == 0) { sEnc[r] = s; qEnc[r] = q; }
    }
    __syncthreads();

    // ---- Phase C: meta gather + conv via in-wave shuffles (two 64-row halves)
    #pragma unroll 1
    for (int rr = 0; rr < 2; ++rr) {
        const int r = (tid >> 3) + rr * 64, k = tid & 7;
        const int s = startsL[r], e = startsL[r + 1];
        float val[8];
        #pragma unroll
        for (int d = 0; d < 8; d++) val[d] = 0.f;
        for (int i = s + k; i < e; i += 8) {
            int id = cat_ids[i];
            const float4 a = *(const float4*)(meta_table + (size_t)id * 8);
            const float4 b = *(const float4*)(meta_table + (size_t)id * 8 + 4);
            val[0] += a.x; val[1] += a.y; val[2] += a.z; val[3] += a.w;
            val[4] += b.x; val[5] += b.y; val[6] += b.z; val[7] += b.w;
        }
        #pragma unroll
        for (int m = 1; m <= 4; m <<= 1)
            #pragma unroll
            for (int d = 0; d < 8; d++) val[d] += __shfl_xor(val[d], m);
        float inv = 1.f / fmaxf((float)(e - s), 1.f);
        if (k == 0) {
            #pragma unroll
            for (int d = 0; d < 8; d++) val[d] *= inv;      // lane 0: avg_cat
        } else if (k <= 5) {
            int id = meta_ids[(size_t)(row0 + r) * 5 + (k - 1)];
            const float4 a = *(const float4*)(meta_table + (size_t)id * 8);
            const float4 b = *(const float4*)(meta_table + (size_t)id * 8 + 4);
            val[0] = a.x; val[1] = a.y; val[2] = a.z; val[3] = a.w;
            val[4] = b.x; val[5] = b.y; val[6] = b.z; val[7] = b.w;
        }
        const int base = lane & 56;
        float mm[6][8];
        #pragma unroll
        for (int src = 0; src < 6; src++)
            #pragma unroll
            for (int d = 0; d < 8; d++)
                mm[src][d] = __shfl(val[d], base + src);
        unsigned short* arow = Alds + r * ASTR;
        float s2 = 0.f, q2 = 0.f;
        if (k < 5) {                        // lane k computes conv output channel oc=k
            const int oc = k;
            float c[6];
            #pragma unroll
            for (int x = 0; x < 6; x++) {
                float a = cbL[oc];
                #pragma unroll
                for (int ic = 0; ic < 6; ic++)
                    #pragma unroll
                    for (int kj = 0; kj < 3; kj++)
                        a = fmaf(mm[ic][x + kj], cwL[(oc * 6 + ic) * 3 + kj], a);
                c[x] = fmaxf(a, 0.f);
            }
            unsigned short o[4];
            #pragma unroll
            for (int x = 0; x < 4; x++) {
                float p = fmaxf(fmaxf(c[x], c[x + 1]), c[x + 2]);
                s2 += p; q2 = fmaf(p, p, q2);
                o[x] = f2bf(p);
            }
            ushort4 st = { o[0], o[1], o[2], o[3] };
            *(ushort4*)(arow + 512 + oc * 4) = st;
        } else {                            // lanes 5,6,7: zero the K-pad cols 532..543
            ushort4 z = { 0, 0, 0, 0 };
            *(ushort4*)(arow + 532 + (k - 5) * 4) = z;
        }
        #pragma unroll
        for (int m = 1; m <= 4; m <<= 1) { s2 += __shfl_xor(s2, m); q2 += __shfl_xor(q2, m); }
        if (k == 0) { sEnc[r] += s2; qEnc[r] += q2; }
    }
    __syncthreads();
    if (tid < BM) {                         // finalize LN1 stats in place: sEnc<-mu, qEnc<-rs
        float mean = sEnc[tid] * (1.f / K1DIM);
        float var  = qEnc[tid] * (1.f / K1DIM) - mean * mean;
        sEnc[tid] = mean;
        qEnc[tid] = rsqrtf(var + LNEPS);
    }
    __syncthreads();

    // ---- GEMM1: two 64-col passes per wave, acc[8][4]=128 AGPR; depth-2 A/B prefetch
    const int ln   = lane & 15;
    const int quad = lane >> 4;
    const unsigned short* aBase = Alds + ln * ASTR + quad * 8;

#define LDA8(A, kk) { _Pragma("unroll") for (int rt = 0; rt < 8; rt++) \
        A[rt] = *(const bf16x8*)(aBase + rt * 16 * ASTR + (kk) * 32); }
#define LDB4(Bv, kk) { _Pragma("unroll") for (int ct = 0; ct < 4; ct++) \
        Bv[ct] = *(const bf16x8*)(bp0 + (size_t)ct * 16 * KPAD + (kk) * 32); }
#define MFM(A, Bv) { _Pragma("unroll") for (int ct = 0; ct < 4; ct++) \
        _Pragma("unroll") for (int rt = 0; rt < 8; rt++) \
        acc[rt][ct] = __builtin_amdgcn_mfma_f32_16x16x32_bf16(A[rt], Bv[ct], acc[rt][ct], 0, 0, 0); }

    #pragma unroll 1
    for (int pass = 0; pass < 2; ++pass) {
        const int cb = pass * 512 + w * 64;
        const unsigned short* bp0 = w1b + (size_t)(cb + ln) * KPAD + quad * 8;

        f32x4 acc[8][4];
        #pragma unroll
        for (int rt = 0; rt < 8; rt++)
            #pragma unroll
            for (int ct = 0; ct < 4; ct++)
                acc[rt][ct] = f32x4{0.f, 0.f, 0.f, 0.f};

        bf16x8 bP[4], bQ[4], aF[8], aG[8];
        LDB4(bP, 0)
        LDB4(bQ, 1)
        #pragma unroll 1
        for (int kk = 0; kk < 16; kk += 2) {
            LDA8(aF, kk)
            MFM(aF, bP)
            LDB4(bP, kk + 2)                     // kk+2 <= 16: always valid
            LDA8(aG, kk + 1)
            MFM(aG, bQ)
            int k3 = (kk + 3 <= 16) ? kk + 3 : 1;
            LDB4(bQ, k3)
        }
        LDA8(aF, 16)
        MFM(aF, bP)

        // epilogue: h = relu(rs*(acc - mu*G) + B0 + b1); DPP-reduce; LDS atomic accumulate
        int colc[4]; float Gv[4], Bv[4], bv[4], vv[6][4];
        #pragma unroll
        for (int ct = 0; ct < 4; ct++) {
            colc[ct] = cb + ct * 16 + ln;
            Gv[ct] = Gc[colc[ct]]; Bv[ct] = B0c[colc[ct]]; bv[ct] = b1[colc[ct]];
            float g2 = ln2_g[colc[ct]];
            #pragma unroll
            for (int j = 0; j < 6; j++) vv[j][ct] = g2 * out_w[j * CD + colc[ct]];
        }
        #pragma unroll
        for (int rt = 0; rt < 8; rt++) {
            #pragma unroll
            for (int reg = 0; reg < 4; reg++) {
                const int row = rt * 16 + quad * 4 + reg;
                const float mu = sEnc[row], rs = qEnc[row];
                float s = 0.f, q = 0.f, p[6];
                #pragma unroll
                for (int j = 0; j < 6; j++) p[j] = 0.f;
                #pragma unroll
                for (int ct = 0; ct < 4; ct++) {
                    float h = fmaxf(rs * (acc[rt][ct][reg] - mu * Gv[ct]) + Bv[ct] + bv[ct], 0.f);
                    s += h; q = fmaf(h, h, q);
                    #pragma unroll
                    for (int j = 0; j < 6; j++) p[j] = fmaf(h, vv[j][ct], p[j]);
                }
                s = dpp_red16(s); q = dpp_red16(q);
                #pragma unroll
                for (int j = 0; j < 6; j++) p[j] = dpp_red16(p[j]);
                if (ln == 15) {                  // full 16-lane sum lives on ln==15 (R6-verified)
                    atomicAdd(&Ssum[row][0], s);
                    atomicAdd(&Ssum[row][1], q);
                    #pragma unroll
                    for (int j = 0; j < 6; j++) atomicAdd(&Ssum[row][2 + j], p[j]);
                }
            }
        }
    }
#undef LDA8
#undef LDB4
#undef MFM
    __syncthreads();

    if (tid < BM) {
        float s = Ssum[tid][0], q = Ssum[tid][1];
        float mean = s * (1.f / CD);
        float var  = q * (1.f / CD) - mean * mean;
        mu2[tid] = mean; rs2[tid] = rsqrtf(var + LNEPS);
    }
    __syncthreads();

    for (int t = tid; t < BM * 6; t += 512) {
        int r = t / 6, j = t - r * 6;
        float S = Ssum[r][2 + j];
        int gr = row0 + r;
        float cs = 0.f;
        #pragma unroll
        for (int jj = 0; jj < 6; jj++) cs += credit[(size_t)gr * 6 + jj];
        float bias = (cs > 0.f) ? credit[(size_t)gr * 6 + j] / cs : (1.f / 6.f);
        out[(size_t)gr * 6 + j] = rs2[r] * S - mu2[r] * rs2[r] * c1L[j] + c0L[j] + bias;
    }
}

// ================= legacy fallback (no workspace) — R3-verified (BM=64) =================
__global__ __launch_bounds__(512, 2) void k_legacy(
    const float* __restrict__ encode, const float* __restrict__ credit,
    const float* __restrict__ meta_table, const float* __restrict__ conv_w,
    const float* __restrict__ conv_b, const float* __restrict__ ln1_g,
    const float* __restrict__ ln1_b, const float* __restrict__ w1f,
    const float* __restrict__ b1,
    const float* __restrict__ ln2_g, const float* __restrict__ ln2_b,
    const float* __restrict__ out_w, const float* __restrict__ out_b,
    const int* __restrict__ meta_ids, const int* __restrict__ cat_ids,
    const int* __restrict__ cat_seg, float* __restrict__ out)
{
    __shared__ unsigned short Alds[64 * ASTR];
    __shared__ float Vlds[6 * CD];
    __shared__ float gL[K1DIM], bL[K1DIM];
    __shared__ float cwL[90], cbL[5];
    __shared__ float mfL[64][20];
    __shared__ float sEnc[64], qEnc[64];
    __shared__ float muL[64], rsL[64];
    __shared__ float rowsum[64][8], rowsq[64][8];
    __shared__ float mu2[64], rs2[64];
    __shared__ float Sbuf[64][6][8];
    __shared__ float c0L[6], c1L[6];
    __shared__ int   startsL[65];
    __shared__ int   sLoL, sHiL;

    const int tid  = threadIdx.x;
    const int row0 = blockIdx.x * 64;
    const int lane = tid & 63;
    const int w    = tid >> 6;

    if (w == 0) {
        if (lane < 2) {
            int target = row0 + lane * 64;
            int lo = 0, hi = NCATS;
            while (lo < hi) { int mid = (lo + hi) >> 1; if (cat_seg[mid] < target) lo = mid + 1; else hi = mid; }
            if (lane == 0) sLoL = lo; else sHiL = lo;
        }
    } else {
        const int t = tid - 64;
        for (int i = t; i < 6 * CD; i += 448) Vlds[i] = ln2_g[i & (CD - 1)] * out_w[i];
        for (int i = t; i < K1DIM; i += 448) { gL[i] = ln1_g[i]; bL[i] = ln1_b[i]; }
        if (t < 90) cwL[t] = conv_w[t];
        if (t < 5)  cbL[t] = conv_b[t];
        for (int r = w - 1; r < 64; r += 7) {
            const float* p = encode + (size_t)(row0 + r) * H + lane * 8;
            float4 v0 = *(const float4*)p;
            float4 v1 = *(const float4*)(p + 4);
            float s = v0.x + v0.y + v0.z + v0.w + v1.x + v1.y + v1.z + v1.w;
            float q = v0.x*v0.x + v0.y*v0.y + v0.z*v0.z + v0.w*v0.w
                    + v1.x*v1.x + v1.y*v1.y + v1.z*v1.z + v1.w*v1.w;
            for (int m = 1; m < 64; m <<= 1) { s += __shfl_xor(s, m); q += __shfl_xor(q, m); }
            if (lane == 0) { sEnc[r] = s; qEnc[r] = q; }
        }
    }
    __syncthreads();

    {
        const int slo = sLoL, shi = sHiL;
        for (int i = slo - 1 + tid; i < shi; i += 512) {
            int a = (i >= 0) ? cat_seg[i] : -1;
            int b = (i + 1 < NCATS) ? cat_seg[i + 1] : BSZ;
            int rlo = max(a + 1, row0);
            int rhi = min(b, row0 + 64);
            for (int r = rlo; r <= rhi; ++r) startsL[r - row0] = i + 1;
        }
    }
    if (w >= 1 && w <= 6) {
        int j = w - 1;
        float s1 = 0.f, s0 = 0.f;
        for (int c = lane; c < CD; c += 64) {
            s1 += Vlds[j * CD + c];
            s0 = fmaf(ln2_b[c], out_w[j * CD + c], s0);
        }
        for (int m = 1; m < 64; m <<= 1) { s1 += __shfl_xor(s1, m); s0 += __shfl_xor(s0, m); }
        if (lane == 0) { c1L[j] = s1; c0L[j] = s0 + out_b[j]; }
    }
    __syncthreads();

    if (tid < 64) {
        const int r = tid;
        const int s = startsL[r], e = startsL[r + 1];
        float mm[6][8];
        float sum[8];
        #pragma unroll
        for (int d = 0; d < 8; d++) sum[d] = 0.f;
        for (int i = s; i < e; i++) {
            int id = cat_ids[i];
            const float4 a = *(const float4*)(meta_table + (size_t)id * 8);
            const float4 b = *(const float4*)(meta_table + (size_t)id * 8 + 4);
            sum[0] += a.x; sum[1] += a.y; sum[2] += a.z; sum[3] += a.w;
            sum[4] += b.x; sum[5] += b.y; sum[6] += b.z; sum[7] += b.w;
        }
        float cnt = fmaxf((float)(e - s), 1.f);
        #pragma unroll
        for (int d = 0; d < 8; d++) mm[0][d] = sum[d] / cnt;
        #pragma unroll
        for (int i = 0; i < 5; i++) {
            int id = meta_ids[(size_t)(row0 + r) * 5 + i];
            const float4 a = *(const float4*)(meta_table + (size_t)id * 8);
            const float4 b = *(const float4*)(meta_table + (size_t)id * 8 + 4);
            mm[1+i][0] = a.x; mm[1+i][1] = a.y; mm[1+i][2] = a.z; mm[1+i][3] = a.w;
            mm[1+i][4] = b.x; mm[1+i][5] = b.y; mm[1+i][6] = b.z; mm[1+i][7] = b.w;
        }
        float mfv[20];
        #pragma unroll
        for (int oc = 0; oc < 5; oc++) {
            float c[6];
            #pragma unroll
            for (int x = 0; x < 6; x++) {
                float a = cbL[oc];
                #pragma unroll
                for (int ic = 0; ic < 6; ic++)
                    #pragma unroll
                    for (int k = 0; k < 3; k++)
                        a = fmaf(mm[ic][x + k], cwL[(oc * 6 + ic) * 3 + k], a);
                c[x] = fmaxf(a, 0.f);
            }
            #pragma unroll
            for (int x = 0; x < 4; x++)
                mfv[oc * 4 + x] = fmaxf(fmaxf(c[x], c[x + 1]), c[x + 2]);
        }
        float sT = sEnc[r], qT = qEnc[r];
        #pragma unroll
        for (int j = 0; j < 20; j++) {
            mfL[r][j] = mfv[j];
            sT += mfv[j]; qT = fmaf(mfv[j], mfv[j], qT);
        }
        float mean = sT * (1.f / K1DIM);
        float var  = qT * (1.f / K1DIM) - mean * mean;
        muL[r] = mean;
        rsL[r] = rsqrtf(var + LNEPS);
    }
    __syncthreads();

    for (int i = tid; i < 64 * 136; i += 512) {
        int r = i / 136, c4 = i - r * 136;
        int col = c4 * 4;
        unsigned short o0 = 0, o1 = 0, o2 = 0, o3 = 0;
        if (c4 < 133) {
            float x0, x1, x2, x3;
            if (c4 < 128) {
                const float4 v = *(const float4*)&encode[(size_t)(row0 + r) * H + col];
                x0 = v.x; x1 = v.y; x2 = v.z; x3 = v.w;
            } else {
                int o = col - H;
                x0 = mfL[r][o]; x1 = mfL[r][o + 1]; x2 = mfL[r][o + 2]; x3 = mfL[r][o + 3];
            }
            float m = muL[r], rr = rsL[r];
            o0 = f2bf((x0 - m) * rr * gL[col + 0] + bL[col + 0]);
            o1 = f2bf((x1 - m) * rr * gL[col + 1] + bL[col + 1]);
            o2 = f2bf((x2 - m) * rr * gL[col + 2] + bL[col + 2]);
            o3 = f2bf((x3 - m) * rr * gL[col + 3] + bL[col + 3]);
        }
        ushort4 st = { o0, o1, o2, o3 };
        *(ushort4*)&Alds[r * ASTR + col] = st;
    }
    __syncthreads();

    const int ln   = lane & 15;
    const int quad = lane >> 4;
    const int cb   = w * 128;

    f32x4 acc[4][8];
    #pragma unroll
    for (int rt = 0; rt < 4; rt++)
        #pragma unroll
        for (int ct = 0; ct < 8; ct++)
            acc[rt][ct] = f32x4{0.f, 0.f, 0.f, 0.f};

    #pragma unroll 1
    for (int kk = 0; kk < 16; kk++) {
        bf16x8 af[4];
        #pragma unroll
        for (int rt = 0; rt < 4; rt++)
            af[rt] = *(const bf16x8*)&Alds[(rt * 16 + ln) * ASTR + kk * 32 + quad * 8];
        #pragma unroll
        for (int ct = 0; ct < 8; ct++) {
            const float* wrow = w1f + (size_t)(cb + ct * 16 + ln) * K1DIM + kk * 32 + quad * 8;
            const float4 fa = *(const float4*)wrow;
            const float4 fb = *(const float4*)(wrow + 4);
            union { bf16x8 v; unsigned int u[4]; } bu;
            bu.u[0] = pack_bf2(fa.x, fa.y);
            bu.u[1] = pack_bf2(fa.z, fa.w);
            bu.u[2] = pack_bf2(fb.x, fb.y);
            bu.u[3] = pack_bf2(fb.z, fb.w);
            #pragma unroll
            for (int rt = 0; rt < 4; rt++)
                acc[rt][ct] = __builtin_amdgcn_mfma_f32_16x16x32_bf16(af[rt], bu.v, acc[rt][ct], 0, 0, 0);
        }
    }
    {
        bf16x8 af[4];
        #pragma unroll
        for (int rt = 0; rt < 4; rt++)
            af[rt] = *(const bf16x8*)&Alds[(rt * 16 + ln) * ASTR + 512 + quad * 8];
        #pragma unroll
        for (int ct = 0; ct < 8; ct++) {
            union { bf16x8 v; unsigned int u[4]; } bu;
            bu.u[0] = 0; bu.u[1] = 0; bu.u[2] = 0; bu.u[3] = 0;
            const float* wrow = w1f + (size_t)(cb + ct * 16 + ln) * K1DIM + 512 + quad * 8;
            if (quad < 2) {
                const float4 fa = *(const float4*)wrow;
                const float4 fb = *(const float4*)(wrow + 4);
                bu.u[0] = pack_bf2(fa.x, fa.y);
                bu.u[1] = pack_bf2(fa.z, fa.w);
                bu.u[2] = pack_bf2(fb.x, fb.y);
                bu.u[3] = pack_bf2(fb.z, fb.w);
            } else if (quad == 2) {
                const float4 fa = *(const float4*)wrow;
                bu.u[0] = pack_bf2(fa.x, fa.y);
                bu.u[1] = pack_bf2(fa.z, fa.w);
            }
            #pragma unroll
            for (int rt = 0; rt < 4; rt++)
                acc[rt][ct] = __builtin_amdgcn_mfma_f32_16x16x32_bf16(af[rt], bu.v, acc[rt][ct], 0, 0, 0);
        }
    }

    float b1v[8]; int colc[8];
    #pragma unroll
    for (int ct = 0; ct < 8; ct++) { colc[ct] = cb + ct * 16 + ln; b1v[ct] = b1[colc[ct]]; }
    #pragma unroll
    for (int rt = 0; rt < 4; rt++)
        #pragma unroll
        for (int ct = 0; ct < 8; ct++)
            #pragma unroll
            for (int reg = 0; reg < 4; reg++)
                acc[rt][ct][reg] = fmaxf(acc[rt][ct][reg] + b1v[ct], 0.f);

    #pragma unroll
    for (int rt = 0; rt < 4; rt++) {
        #pragma unroll
        for (int reg = 0; reg < 4; reg++) {
            float s = 0.f, q = 0.f;
            #pragma unroll
            for (int ct = 0; ct < 8; ct++) { float f = acc[rt][ct][reg]; s += f; q = fmaf(f, f, q); }
            #pragma unroll
            for (int m = 1; m <= 8; m <<= 1) { s += __shfl_xor(s, m); q += __shfl_xor(q, m); }
            if (ln == 0) {
                int row = rt * 16 + quad * 4 + reg;
                rowsum[row][w] = s; rowsq[row][w] = q;
            }
        }
    }
    __syncthreads();
    if (tid < 64) {
        float s = 0.f, q = 0.f;
        #pragma unroll
        for (int ww = 0; ww < 8; ww++) { s += rowsum[tid][ww]; q += rowsq[tid][ww]; }
        float mean = s * (1.f / CD);
        float var  = q * (1.f / CD) - mean * mean;
        mu2[tid] = mean; rs2[tid] = rsqrtf(var + LNEPS);
    }

    float vv[6][8];
    #pragma unroll
    for (int j = 0; j < 6; j++)
        #pragma unroll
        for (int ct = 0; ct < 8; ct++)
            vv[j][ct] = Vlds[j * CD + colc[ct]];
    #pragma unroll
    for (int rt = 0; rt < 4; rt++) {
        #pragma unroll
        for (int reg = 0; reg < 4; reg++) {
            float p0 = 0.f, p1 = 0.f, p2 = 0.f, p3 = 0.f, p4 = 0.f, p5 = 0.f;
            #pragma unroll
            for (int ct = 0; ct < 8; ct++) {
                float f = acc[rt][ct][reg];
                p0 = fmaf(f, vv[0][ct], p0); p1 = fmaf(f, vv[1][ct], p1);
                p2 = fmaf(f, vv[2][ct], p2); p3 = fmaf(f, vv[3][ct], p3);
                p4 = fmaf(f, vv[4][ct], p4); p5 = fmaf(f, vv[5][ct], p5);
            }
            #pragma unroll
            for (int m = 1; m <= 8; m <<= 1) {
                p0 += __shfl_xor(p0, m); p1 += __shfl_xor(p1, m); p2 += __shfl_xor(p2, m);
                p3 += __shfl_xor(p3, m); p4 += __shfl_xor(p4, m); p5 += __shfl_xor(p5, m);
            }
            if (ln == 0) {
                int row = rt * 16 + quad * 4 + reg;
                Sbuf[row][0][w] = p0; Sbuf[row][1][w] = p1; Sbuf[row][2][w] = p2;
                Sbuf[row][3][w] = p3; Sbuf[row][4][w] = p4; Sbuf[row][5][w] = p5;
            }
        }
    }
    __syncthreads();

    if (tid < 384) {
        int r = tid / 6, j = tid - r * 6;
        float S = 0.f;
        #pragma unroll
        for (int ww = 0; ww < 8; ww++) S += Sbuf[r][j][ww];
        int gr = row0 + r;
        float cs = 0.f;
        #pragma unroll
        for (int jj = 0; jj < 6; jj++) cs += credit[(size_t)gr * 6 + jj];
        float bias = (cs > 0.f) ? credit[(size_t)gr * 6 + j] / cs : (1.f / 6.f);
        out[(size_t)gr * 6 + j] = rs2[r] * S - mu2[r] * rs2[r] * c1L[j] + c0L[j] + bias;
    }
}

extern "C" void kernel_launch(void* const* d_in, const int* in_sizes, int n_in,
                              void* d_out, int out_size, void* d_ws, size_t ws_size,
                              hipStream_t stream) {
    const float* encode     = (const float*)d_in[0];
    const float* credit     = (const float*)d_in[1];
    const float* meta_table = (const float*)d_in[2];
    const float* conv_w     = (const float*)d_in[3];
    const float* conv_b     = (const float*)d_in[4];
    const float* ln1_g      = (const float*)d_in[5];
    const float* ln1_b      = (const float*)d_in[6];
    const float* mlp1_w     = (const float*)d_in[7];
    const float* mlp1_b     = (const float*)d_in[8];
    const float* ln2_g      = (const float*)d_in[9];
    const float* ln2_b      = (const float*)d_in[10];
    const float* out_w      = (const float*)d_in[11];
    const float* out_b      = (const float*)d_in[12];
    const int*   meta_ids   = (const int*)d_in[13];
    const int*   cat_ids    = (const int*)d_in[14];
    const int*   cat_seg    = (const int*)d_in[15];
    float* out = (float*)d_out;

    // ws layout: w1b (g-folded bf16) | G | B0 | c0 | c1
    const size_t OFF_G  = (size_t)CD * KPAD * sizeof(unsigned short);   // 1,114,112
    const size_t OFF_B0 = OFF_G + CD * sizeof(float);
    const size_t OFF_C0 = OFF_B0 + CD * sizeof(float);
    const size_t OFF_C1 = OFF_C0 + 32;
    const size_t WS_NEED = OFF_C1 + 32;                                 // 1,122,432

    if (ws_size >= WS_NEED) {
        char* ws = (char*)d_ws;
        unsigned short* w1b = (unsigned short*)ws;
        float* G  = (float*)(ws + OFF_G);
        float* B0 = (float*)(ws + OFF_B0);
        float* c0 = (float*)(ws + OFF_C0);
        float* c1 = (float*)(ws + OFF_C1);
        k_prep<<<2433, 256, 0, stream>>>(mlp1_w, ln1_g, ln1_b, ln2_g, ln2_b, out_w, out_b,
                                         w1b, G, B0, c0, c1);
        k_mainw<<<BSZ / BM, 512, 0, stream>>>(
            encode, credit, meta_table, conv_w, conv_b,
            w1b, mlp1_b, ln2_g, out_w, G, B0, c0, c1,
            meta_ids, cat_ids, cat_seg, out);
    } else {
        k_legacy<<<BSZ / 64, 512, 0, stream>>>(
            encode, credit, meta_table, conv_w, conv_b, ln1_g, ln1_b,
            mlp1_w, mlp1_b, ln2_g, ln2_b, out_w, out_b,
            meta_ids, cat_ids, cat_seg, out);
    }
}

// Round 12
// 226.999 us; speedup vs baseline: 1.6100x; 1.6100x over previous
//
#include <hip/hip_runtime.h>

#define BSZ   32768
#define H     512
#define K1DIM 532      // H + 20
#define KPAD  544      // padded to multiple of 32 (ws path)
#define ASTR  552      // LDS A row stride in shorts (2-way bank aliasing only)
#define BM    128      // rows per block (R7 evidence: BM=64/2-blocks regressed timed +8.7%)
#define CD    1024
#define NCATS 262144
#define LNEPS 1e-6f
#define PREP_BLKS 128  // R12: fence cost scales with wave count (R11: 9732 waves = 167us)

typedef short bf16x8 __attribute__((ext_vector_type(8)));   // 8 bf16 in 4 VGPRs
typedef float f32x4  __attribute__((ext_vector_type(4)));

__device__ __forceinline__ unsigned short f2bf(float x) {
    unsigned int u = __float_as_uint(x);
    u += 0x7FFFu + ((u >> 16) & 1u);        // RNE
    return (unsigned short)(u >> 16);
}

__device__ __forceinline__ unsigned int pack_bf2(float lo, float hi) {
    return __builtin_amdgcn_perm(__float_as_uint(hi), __float_as_uint(lo), 0x07060302u);
}

// sum over 16 contiguous lanes via DPP only; full sum valid on ln==15 (R6-verified)
__device__ __forceinline__ float dpp_red16(float x) {
    x += __int_as_float(__builtin_amdgcn_update_dpp(0, __float_as_int(x), 0xB1, 0xf, 0xf, true)); // quad_perm [1,0,3,2]
    x += __int_as_float(__builtin_amdgcn_update_dpp(0, __float_as_int(x), 0x4E, 0xf, 0xf, true)); // quad_perm [2,3,0,1]
    x += __int_as_float(__builtin_amdgcn_update_dpp(0, __float_as_int(x), 0x114, 0xf, 0xf, true)); // row_shr:4
    x += __int_as_float(__builtin_amdgcn_update_dpp(0, __float_as_int(x), 0x118, 0xf, 0xf, true)); // row_shr:8
    return x;
}

// p-ary lower_bound over sorted cat_seg: 3 rounds of 64 probes (one wave) — R6-verified
__device__ __forceinline__ int psearch64(const int* __restrict__ seg, int target) {
    int lane = threadIdx.x & 63;
    int lo = 0, step = 4096;
    #pragma unroll
    for (int lvl = 0; lvl < 3; ++lvl) {
        int idx = lo + lane * step;
        bool lt = (idx < NCATS) && (seg[idx < NCATS ? idx : NCATS - 1] < target);
        unsigned long long m = __ballot(lt);
        int c = __popcll(m);
        if (c > 0) lo = lo + (c - 1) * step + 1;
        step >>= 6;
    }
    return lo;
}

// ---------- merged prep: w1 fold+convert | G/B0 columns | c0/c1 ----------
// R11 evidence: the trailing release __threadfence() costs ~0.14us per wave per XCD
// (2433 blocks x 4 waves = 9732 waves -> 167us of serialized L2 writeback).
// R12: 128 blocks x 256 threads (512 waves) with grid-stride loops -> ~9us fence.
// Per-thread fence retained: every ws-producing thread fences AFTER its own writes
// (memory-model-correct, no dispatch-placement assumptions).
__global__ void k_prep(const float* __restrict__ w1f, const float* __restrict__ ln1_g,
                       const float* __restrict__ ln1_b, const float* __restrict__ ln2_g,
                       const float* __restrict__ ln2_b, const float* __restrict__ out_w,
                       const float* __restrict__ out_b,
                       unsigned short* __restrict__ w1b, float* __restrict__ G,
                       float* __restrict__ B0, float* __restrict__ c0, float* __restrict__ c1) {
    const int bid = blockIdx.x, tid = threadIdx.x;
    const int lane = tid & 63, w = tid >> 6;

    // w1b fold+convert: grid-stride over CD*KPAD = 557056 (17 iters/thread)
    for (int idx = bid * 256 + tid; idx < CD * KPAD; idx += PREP_BLKS * 256) {
        int row = idx / KPAD, k = idx - row * KPAD;
        float v = (k < K1DIM) ? w1f[(size_t)row * K1DIM + k] * ln1_g[k] : 0.f;  // fold ln1_g
        w1b[idx] = f2bf(v);
    }

    // G/B0: 8 cols per block (2 per wave); 128*8 = 1024 = CD
    #pragma unroll
    for (int c = 0; c < 2; ++c) {
        int col = bid * 8 + w * 2 + c;
        float g = 0.f, b = 0.f;
        for (int k = lane; k < K1DIM; k += 64) {
            float wv = w1f[(size_t)col * K1DIM + k];
            g = fmaf(ln1_g[k], wv, g);
            b = fmaf(ln1_b[k], wv, b);
        }
        #pragma unroll
        for (int m = 1; m < 64; m <<= 1) { g += __shfl_xor(g, m); b += __shfl_xor(b, m); }
        if (lane == 0) { G[col] = g; B0[col] = b; }
    }

    // c0/c1: blocks 0..5, wave 0 (j = bid)
    if (bid < 6 && w == 0) {
        int j = bid;
        float s1 = 0.f, s0 = 0.f;
        for (int c = lane; c < CD; c += 64) {
            float wv = out_w[j * CD + c];
            s1 = fmaf(ln2_g[c], wv, s1);
            s0 = fmaf(ln2_b[c], wv, s0);
        }
        #pragma unroll
        for (int m = 1; m < 64; m <<= 1) { s1 += __shfl_xor(s1, m); s0 += __shfl_xor(s0, m); }
        if (lane == 0) { c1[j] = s1; c0[j] = s0 + out_b[j]; }
    }

    __threadfence();     // RELEASE: write back this thread's ws stores to L3/HBM
}

// ================= ws-path fused kernel: BM=128, 1 block/CU, 2 waves/SIMD =================
// R11-verified: entry acquire fence makes the graph-replay ws handoff correct.
__global__ __launch_bounds__(512, 2) void k_mainw(
    const float* __restrict__ encode, const float* __restrict__ credit,
    const float* __restrict__ meta_table, const float* __restrict__ conv_w,
    const float* __restrict__ conv_b,
    const unsigned short* __restrict__ w1b, const float* __restrict__ b1,
    const float* __restrict__ ln2_g, const float* __restrict__ out_w,
    const float* __restrict__ Gc, const float* __restrict__ B0c,
    const float* __restrict__ c0p, const float* __restrict__ c1p,
    const int* __restrict__ meta_ids, const int* __restrict__ cat_ids,
    const int* __restrict__ cat_seg, float* __restrict__ out)
{
    __shared__ unsigned short Alds[BM * ASTR];   // 141312 B (raw bf16 x; ln1_g folded into W)
    __shared__ float Ssum[BM][10];               // 5120 B  [row][s,q,p0..5,pad,pad] — atomic acc
    __shared__ float cwL[90], cbL[5];
    __shared__ float sEnc[BM], qEnc[BM];         // stats, then overwritten with mu/rs
    __shared__ float mu2[BM], rs2[BM];
    __shared__ float c0L[6], c1L[6];
    __shared__ int   startsL[BM + 1];
    __shared__ int   sLoL, sHiL;

    __threadfence();     // ACQUIRE: discard stale L2 lines (graph replay elides driver inv)

    const int tid  = threadIdx.x;
    const int row0 = blockIdx.x * BM;
    const int lane = tid & 63;
    const int w    = tid >> 6;

    // ---- Phase A: p-ary boundary searches (waves 0,1) || constants (rest) + zero Ssum
    if (w == 0) {
        int L = psearch64(cat_seg, row0);
        if (lane == 0) sLoL = L;
    } else if (w == 1) {
        int L = psearch64(cat_seg, row0 + BM);
        if (lane == 0) sHiL = L;
    } else {
        const int t = tid - 128;
        if (t < 90) cwL[t] = conv_w[t];
        else if (t < 95) cbL[t - 90] = conv_b[t - 90];
        else if (t < 101) c0L[t - 95] = c0p[t - 95];
        else if (t < 107) c1L[t - 101] = c1p[t - 101];
    }
    for (int i = tid; i < BM * 10; i += 512) ((float*)Ssum)[i] = 0.f;
    __syncthreads();

    // ---- Phase B: boundary scan + encode staging/stats (two 64-row halves, 8 lanes/row)
    {
        const int slo = sLoL, shi = sHiL;
        for (int i = slo - 1 + tid; i < shi; i += 512) {
            int a = (i >= 0) ? cat_seg[i] : -1;
            int b = (i + 1 < NCATS) ? cat_seg[i + 1] : BSZ;
            int rlo = max(a + 1, row0);
            int rhi = min(b, row0 + BM);
            for (int r = rlo; r <= rhi; ++r) startsL[r - row0] = i + 1;
        }
    }
    #pragma unroll
    for (int rr = 0; rr < 2; ++rr) {
        const int r  = (tid >> 3) + rr * 64;
        const int cl = tid & 7;
        const float* erow = encode + (size_t)(row0 + r) * H;
        unsigned short* arow = Alds + r * ASTR;
        float s = 0.f, q = 0.f;
        #pragma unroll 4
        for (int i = 0; i < 16; i++) {
            int col = cl * 4 + i * 32;
            const float4 v = *(const float4*)(erow + col);
            s += v.x + v.y + v.z + v.w;
            q += v.x*v.x + v.y*v.y + v.z*v.z + v.w*v.w;
            ushort4 st = { f2bf(v.x), f2bf(v.y), f2bf(v.z), f2bf(v.w) };
            *(ushort4*)(arow + col) = st;
        }
        #pragma unroll
        for (int m = 1; m <= 4; m <<= 1) { s += __shfl_xor(s, m); q += __shfl_xor(q, m); }
        if (cl == 0) { sEnc[r] = s; qEnc[r] = q; }
    }
    __syncthreads();

    // ---- Phase C: meta gather + conv via in-wave shuffles (two 64-row halves)
    #pragma unroll 1
    for (int rr = 0; rr < 2; ++rr) {
        const int r = (tid >> 3) + rr * 64, k = tid & 7;
        const int s = startsL[r], e = startsL[r + 1];
        float val[8];
        #pragma unroll
        for (int d = 0; d < 8; d++) val[d] = 0.f;
        for (int i = s + k; i < e; i += 8) {
            int id = cat_ids[i];
            const float4 a = *(const float4*)(meta_table + (size_t)id * 8);
            const float4 b = *(const float4*)(meta_table + (size_t)id * 8 + 4);
            val[0] += a.x; val[1] += a.y; val[2] += a.z; val[3] += a.w;
            val[4] += b.x; val[5] += b.y; val[6] += b.z; val[7] += b.w;
        }
        #pragma unroll
        for (int m = 1; m <= 4; m <<= 1)
            #pragma unroll
            for (int d = 0; d < 8; d++) val[d] += __shfl_xor(val[d], m);
        float inv = 1.f / fmaxf((float)(e - s), 1.f);
        if (k == 0) {
            #pragma unroll
            for (int d = 0; d < 8; d++) val[d] *= inv;      // lane 0: avg_cat
        } else if (k <= 5) {
            int id = meta_ids[(size_t)(row0 + r) * 5 + (k - 1)];
            const float4 a = *(const float4*)(meta_table + (size_t)id * 8);
            const float4 b = *(const float4*)(meta_table + (size_t)id * 8 + 4);
            val[0] = a.x; val[1] = a.y; val[2] = a.z; val[3] = a.w;
            val[4] = b.x; val[5] = b.y; val[6] = b.z; val[7] = b.w;
        }
        const int base = lane & 56;
        float mm[6][8];
        #pragma unroll
        for (int src = 0; src < 6; src++)
            #pragma unroll
            for (int d = 0; d < 8; d++)
                mm[src][d] = __shfl(val[d], base + src);
        unsigned short* arow = Alds + r * ASTR;
        float s2 = 0.f, q2 = 0.f;
        if (k < 5) {                        // lane k computes conv output channel oc=k
            const int oc = k;
            float c[6];
            #pragma unroll
            for (int x = 0; x < 6; x++) {
                float a = cbL[oc];
                #pragma unroll
                for (int ic = 0; ic < 6; ic++)
                    #pragma unroll
                    for (int kj = 0; kj < 3; kj++)
                        a = fmaf(mm[ic][x + kj], cwL[(oc * 6 + ic) * 3 + kj], a);
                c[x] = fmaxf(a, 0.f);
            }
            unsigned short o[4];
            #pragma unroll
            for (int x = 0; x < 4; x++) {
                float p = fmaxf(fmaxf(c[x], c[x + 1]), c[x + 2]);
                s2 += p; q2 = fmaf(p, p, q2);
                o[x] = f2bf(p);
            }
            ushort4 st = { o[0], o[1], o[2], o[3] };
            *(ushort4*)(arow + 512 + oc * 4) = st;
        } else {                            // lanes 5,6,7: zero the K-pad cols 532..543
            ushort4 z = { 0, 0, 0, 0 };
            *(ushort4*)(arow + 532 + (k - 5) * 4) = z;
        }
        #pragma unroll
        for (int m = 1; m <= 4; m <<= 1) { s2 += __shfl_xor(s2, m); q2 += __shfl_xor(q2, m); }
        if (k == 0) { sEnc[r] += s2; qEnc[r] += q2; }
    }
    __syncthreads();
    if (tid < BM) {                         // finalize LN1 stats in place: sEnc<-mu, qEnc<-rs
        float mean = sEnc[tid] * (1.f / K1DIM);
        float var  = qEnc[tid] * (1.f / K1DIM) - mean * mean;
        sEnc[tid] = mean;
        qEnc[tid] = rsqrtf(var + LNEPS);
    }
    __syncthreads();

    // ---- GEMM1: two 64-col passes per wave, acc[8][4]=128 AGPR; depth-2 A/B prefetch
    const int ln   = lane & 15;
    const int quad = lane >> 4;
    const unsigned short* aBase = Alds + ln * ASTR + quad * 8;

#define LDA8(A, kk) { _Pragma("unroll") for (int rt = 0; rt < 8; rt++) \
        A[rt] = *(const bf16x8*)(aBase + rt * 16 * ASTR + (kk) * 32); }
#define LDB4(Bv, kk) { _Pragma("unroll") for (int ct = 0; ct < 4; ct++) \
        Bv[ct] = *(const bf16x8*)(bp0 + (size_t)ct * 16 * KPAD + (kk) * 32); }
#define MFM(A, Bv) { _Pragma("unroll") for (int ct = 0; ct < 4; ct++) \
        _Pragma("unroll") for (int rt = 0; rt < 8; rt++) \
        acc[rt][ct] = __builtin_amdgcn_mfma_f32_16x16x32_bf16(A[rt], Bv[ct], acc[rt][ct], 0, 0, 0); }

    #pragma unroll 1
    for (int pass = 0; pass < 2; ++pass) {
        const int cb = pass * 512 + w * 64;
        const unsigned short* bp0 = w1b + (size_t)(cb + ln) * KPAD + quad * 8;

        f32x4 acc[8][4];
        #pragma unroll
        for (int rt = 0; rt < 8; rt++)
            #pragma unroll
            for (int ct = 0; ct < 4; ct++)
                acc[rt][ct] = f32x4{0.f, 0.f, 0.f, 0.f};

        bf16x8 bP[4], bQ[4], aF[8], aG[8];
        LDB4(bP, 0)
        LDB4(bQ, 1)
        #pragma unroll 1
        for (int kk = 0; kk < 16; kk += 2) {
            LDA8(aF, kk)
            MFM(aF, bP)
            LDB4(bP, kk + 2)                     // kk+2 <= 16: always valid
            LDA8(aG, kk + 1)
            MFM(aG, bQ)
            int k3 = (kk + 3 <= 16) ? kk + 3 : 1;
            LDB4(bQ, k3)
        }
        LDA8(aF, 16)
        MFM(aF, bP)

        // epilogue: h = relu(rs*(acc - mu*G) + B0 + b1); DPP-reduce; LDS atomic accumulate
        int colc[4]; float Gv[4], Bv[4], bv[4], vv[6][4];
        #pragma unroll
        for (int ct = 0; ct < 4; ct++) {
            colc[ct] = cb + ct * 16 + ln;
            Gv[ct] = Gc[colc[ct]]; Bv[ct] = B0c[colc[ct]]; bv[ct] = b1[colc[ct]];
            float g2 = ln2_g[colc[ct]];
            #pragma unroll
            for (int j = 0; j < 6; j++) vv[j][ct] = g2 * out_w[j * CD + colc[ct]];
        }
        #pragma unroll
        for (int rt = 0; rt < 8; rt++) {
            #pragma unroll
            for (int reg = 0; reg < 4; reg++) {
                const int row = rt * 16 + quad * 4 + reg;
                const float mu = sEnc[row], rs = qEnc[row];
                float s = 0.f, q = 0.f, p[6];
                #pragma unroll
                for (int j = 0; j < 6; j++) p[j] = 0.f;
                #pragma unroll
                for (int ct = 0; ct < 4; ct++) {
                    float h = fmaxf(rs * (acc[rt][ct][reg] - mu * Gv[ct]) + Bv[ct] + bv[ct], 0.f);
                    s += h; q = fmaf(h, h, q);
                    #pragma unroll
                    for (int j = 0; j < 6; j++) p[j] = fmaf(h, vv[j][ct], p[j]);
                }
                s = dpp_red16(s); q = dpp_red16(q);
                #pragma unroll
                for (int j = 0; j < 6; j++) p[j] = dpp_red16(p[j]);
                if (ln == 15) {                  // full 16-lane sum lives on ln==15 (R6-verified)
                    atomicAdd(&Ssum[row][0], s);
                    atomicAdd(&Ssum[row][1], q);
                    #pragma unroll
                    for (int j = 0; j < 6; j++) atomicAdd(&Ssum[row][2 + j], p[j]);
                }
            }
        }
    }
#undef LDA8
#undef LDB4
#undef MFM
    __syncthreads();

    if (tid < BM) {
        float s = Ssum[tid][0], q = Ssum[tid][1];
        float mean = s * (1.f / CD);
        float var  = q * (1.f / CD) - mean * mean;
        mu2[tid] = mean; rs2[tid] = rsqrtf(var + LNEPS);
    }
    __syncthreads();

    for (int t = tid; t < BM * 6; t += 512) {
        int r = t / 6, j = t - r * 6;
        float S = Ssum[r][2 + j];
        int gr = row0 + r;
        float cs = 0.f;
        #pragma unroll
        for (int jj = 0; jj < 6; jj++) cs += credit[(size_t)gr * 6 + jj];
        float bias = (cs > 0.f) ? credit[(size_t)gr * 6 + j] / cs : (1.f / 6.f);
        out[(size_t)gr * 6 + j] = rs2[r] * S - mu2[r] * rs2[r] * c1L[j] + c0L[j] + bias;
    }
}

// ================= legacy fallback (no workspace) — R3-verified (BM=64) =================
__global__ __launch_bounds__(512, 2) void k_legacy(
    const float* __restrict__ encode, const float* __restrict__ credit,
    const float* __restrict__ meta_table, const float* __restrict__ conv_w,
    const float* __restrict__ conv_b, const float* __restrict__ ln1_g,
    const float* __restrict__ ln1_b, const float* __restrict__ w1f,
    const float* __restrict__ b1,
    const float* __restrict__ ln2_g, const float* __restrict__ ln2_b,
    const float* __restrict__ out_w, const float* __restrict__ out_b,
    const int* __restrict__ meta_ids, const int* __restrict__ cat_ids,
    const int* __restrict__ cat_seg, float* __restrict__ out)
{
    __shared__ unsigned short Alds[64 * ASTR];
    __shared__ float Vlds[6 * CD];
    __shared__ float gL[K1DIM], bL[K1DIM];
    __shared__ float cwL[90], cbL[5];
    __shared__ float mfL[64][20];
    __shared__ float sEnc[64], qEnc[64];
    __shared__ float muL[64], rsL[64];
    __shared__ float rowsum[64][8], rowsq[64][8];
    __shared__ float mu2[64], rs2[64];
    __shared__ float Sbuf[64][6][8];
    __shared__ float c0L[6], c1L[6];
    __shared__ int   startsL[65];
    __shared__ int   sLoL, sHiL;

    const int tid  = threadIdx.x;
    const int row0 = blockIdx.x * 64;
    const int lane = tid & 63;
    const int w    = tid >> 6;

    if (w == 0) {
        if (lane < 2) {
            int target = row0 + lane * 64;
            int lo = 0, hi = NCATS;
            while (lo < hi) { int mid = (lo + hi) >> 1; if (cat_seg[mid] < target) lo = mid + 1; else hi = mid; }
            if (lane == 0) sLoL = lo; else sHiL = lo;
        }
    } else {
        const int t = tid - 64;
        for (int i = t; i < 6 * CD; i += 448) Vlds[i] = ln2_g[i & (CD - 1)] * out_w[i];
        for (int i = t; i < K1DIM; i += 448) { gL[i] = ln1_g[i]; bL[i] = ln1_b[i]; }
        if (t < 90) cwL[t] = conv_w[t];
        if (t < 5)  cbL[t] = conv_b[t];
        for (int r = w - 1; r < 64; r += 7) {
            const float* p = encode + (size_t)(row0 + r) * H + lane * 8;
            float4 v0 = *(const float4*)p;
            float4 v1 = *(const float4*)(p + 4);
            float s = v0.x + v0.y + v0.z + v0.w + v1.x + v1.y + v1.z + v1.w;
            float q = v0.x*v0.x + v0.y*v0.y + v0.z*v0.z + v0.w*v0.w
                    + v1.x*v1.x + v1.y*v1.y + v1.z*v1.z + v1.w*v1.w;
            for (int m = 1; m < 64; m <<= 1) { s += __shfl_xor(s, m); q += __shfl_xor(q, m); }
            if (lane == 0) { sEnc[r] = s; qEnc[r] = q; }
        }
    }
    __syncthreads();

    {
        const int slo = sLoL, shi = sHiL;
        for (int i = slo - 1 + tid; i < shi; i += 512) {
            int a = (i >= 0) ? cat_seg[i] : -1;
            int b = (i + 1 < NCATS) ? cat_seg[i + 1] : BSZ;
            int rlo = max(a + 1, row0);
            int rhi = min(b, row0 + 64);
            for (int r = rlo; r <= rhi; ++r) startsL[r - row0] = i + 1;
        }
    }
    if (w >= 1 && w <= 6) {
        int j = w - 1;
        float s1 = 0.f, s0 = 0.f;
        for (int c = lane; c < CD; c += 64) {
            s1 += Vlds[j * CD + c];
            s0 = fmaf(ln2_b[c], out_w[j * CD + c], s0);
        }
        for (int m = 1; m < 64; m <<= 1) { s1 += __shfl_xor(s1, m); s0 += __shfl_xor(s0, m); }
        if (lane == 0) { c1L[j] = s1; c0L[j] = s0 + out_b[j]; }
    }
    __syncthreads();

    if (tid < 64) {
        const int r = tid;
        const int s = startsL[r], e = startsL[r + 1];
        float mm[6][8];
        float sum[8];
        #pragma unroll
        for (int d = 0; d < 8; d++) sum[d] = 0.f;
        for (int i = s; i < e; i++) {
            int id = cat_ids[i];
            const float4 a = *(const float4*)(meta_table + (size_t)id * 8);
            const float4 b = *(const float4*)(meta_table + (size_t)id * 8 + 4);
            sum[0] += a.x; sum[1] += a.y; sum[2] += a.z; sum[3] += a.w;
            sum[4] += b.x; sum[5] += b.y; sum[6] += b.z; sum[7] += b.w;
        }
        float cnt = fmaxf((float)(e - s), 1.f);
        #pragma unroll
        for (int d = 0; d < 8; d++) mm[0][d] = sum[d] / cnt;
        #pragma unroll
        for (int i = 0; i < 5; i++) {
            int id = meta_ids[(size_t)(row0 + r) * 5 + i];
            const float4 a = *(const float4*)(meta_table + (size_t)id * 8);
            const float4 b = *(const float4*)(meta_table + (size_t)id * 8 + 4);
            mm[1+i][0] = a.x; mm[1+i][1] = a.y; mm[1+i][2] = a.z; mm[1+i][3] = a.w;
            mm[1+i][4] = b.x; mm[1+i][5] = b.y; mm[1+i][6] = b.z; mm[1+i][7] = b.w;
        }
        float mfv[20];
        #pragma unroll
        for (int oc = 0; oc < 5; oc++) {
            float c[6];
            #pragma unroll
            for (int x = 0; x < 6; x++) {
                float a = cbL[oc];
                #pragma unroll
                for (int ic = 0; ic < 6; ic++)
                    #pragma unroll
                    for (int k = 0; k < 3; k++)
                        a = fmaf(mm[ic][x + k], cwL[(oc * 6 + ic) * 3 + k], a);
                c[x] = fmaxf(a, 0.f);
            }
            #pragma unroll
            for (int x = 0; x < 4; x++)
                mfv[oc * 4 + x] = fmaxf(fmaxf(c[x], c[x + 1]), c[x + 2]);
        }
        float sT = sEnc[r], qT = qEnc[r];
        #pragma unroll
        for (int j = 0; j < 20; j++) {
            mfL[r][j] = mfv[j];
            sT += mfv[j]; qT = fmaf(mfv[j], mfv[j], qT);
        }
        float mean = sT * (1.f / K1DIM);
        float var  = qT * (1.f / K1DIM) - mean * mean;
        muL[r] = mean;
        rsL[r] = rsqrtf(var + LNEPS);
    }
    __syncthreads();

    for (int i = tid; i < 64 * 136; i += 512) {
        int r = i / 136, c4 = i - r * 136;
        int col = c4 * 4;
        unsigned short o0 = 0, o1 = 0, o2 = 0, o3 = 0;
        if (c4 < 133) {
            float x0, x1, x2, x3;
            if (c4 < 128) {
                const float4 v = *(const float4*)&encode[(size_t)(row0 + r) * H + col];
                x0 = v.x; x1 = v.y; x2 = v.z; x3 = v.w;
            } else {
                int o = col - H;
                x0 = mfL[r][o]; x1 = mfL[r][o + 1]; x2 = mfL[r][o + 2]; x3 = mfL[r][o + 3];
            }
            float m = muL[r], rr = rsL[r];
            o0 = f2bf((x0 - m) * rr * gL[col + 0] + bL[col + 0]);
            o1 = f2bf((x1 - m) * rr * gL[col + 1] + bL[col + 1]);
            o2 = f2bf((x2 - m) * rr * gL[col + 2] + bL[col + 2]);
            o3 = f2bf((x3 - m) * rr * gL[col + 3] + bL[col + 3]);
        }
        ushort4 st = { o0, o1, o2, o3 };
        *(ushort4*)&Alds[r * ASTR + col] = st;
    }
    __syncthreads();

    const int ln   = lane & 15;
    const int quad = lane >> 4;
    const int cb   = w * 128;

    f32x4 acc[4][8];
    #pragma unroll
    for (int rt = 0; rt < 4; rt++)
        #pragma unroll
        for (int ct = 0; ct < 8; ct++)
            acc[rt][ct] = f32x4{0.f, 0.f, 0.f, 0.f};

    #pragma unroll 1
    for (int kk = 0; kk < 16; kk++) {
        bf16x8 af[4];
        #pragma unroll
        for (int rt = 0; rt < 4; rt++)
            af[rt] = *(const bf16x8*)&Alds[(rt * 16 + ln) * ASTR + kk * 32 + quad * 8];
        #pragma unroll
        for (int ct = 0; ct < 8; ct++) {
            const float* wrow = w1f + (size_t)(cb + ct * 16 + ln) * K1DIM + kk * 32 + quad * 8;
            const float4 fa = *(const float4*)wrow;
            const float4 fb = *(const float4*)(wrow + 4);
            union { bf16x8 v; unsigned int u[4]; } bu;
            bu.u[0] = pack_bf2(fa.x, fa.y);
            bu.u[1] = pack_bf2(fa.z, fa.w);
            bu.u[2] = pack_bf2(fb.x, fb.y);
            bu.u[3] = pack_bf2(fb.z, fb.w);
            #pragma unroll
            for (int rt = 0; rt < 4; rt++)
                acc[rt][ct] = __builtin_amdgcn_mfma_f32_16x16x32_bf16(af[rt], bu.v, acc[rt][ct], 0, 0, 0);
        }
    }
    {
        bf16x8 af[4];
        #pragma unroll
        for (int rt = 0; rt < 4; rt++)
            af[rt] = *(const bf16x8*)&Alds[(rt * 16 + ln) * ASTR + 512 + quad * 8];
        #pragma unroll
        for (int ct = 0; ct < 8; ct++) {
            union { bf16x8 v; unsigned int u[4]; } bu;
            bu.u[0] = 0; bu.u[1] = 0; bu.u[2] = 0; bu.u[3] = 0;
            const float* wrow = w1f + (size_t)(cb + ct * 16 + ln) * K1DIM + 512 + quad * 8;
            if (quad < 2) {
                const float4 fa = *(const float4*)wrow;
                const float4 fb = *(const float4*)(wrow + 4);
                bu.u[0] = pack_bf2(fa.x, fa.y);
                bu.u[1] = pack_bf2(fa.z, fa.w);
                bu.u[2] = pack_bf2(fb.x, fb.y);
                bu.u[3] = pack_bf2(fb.z, fb.w);
            } else if (quad == 2) {
                const float4 fa = *(const float4*)wrow;
                bu.u[0] = pack_bf2(fa.x, fa.y);
                bu.u[1] = pack_bf2(fa.z, fa.w);
            }
            #pragma unroll
            for (int rt = 0; rt < 4; rt++)
                acc[rt][ct] = __builtin_amdgcn_mfma_f32_16x16x32_bf16(af[rt], bu.v, acc[rt][ct], 0, 0, 0);
        }
    }

    float b1v[8]; int colc[8];
    #pragma unroll
    for (int ct = 0; ct < 8; ct++) { colc[ct] = cb + ct * 16 + ln; b1v[ct] = b1[colc[ct]]; }
    #pragma unroll
    for (int rt = 0; rt < 4; rt++)
        #pragma unroll
        for (int ct = 0; ct < 8; ct++)
            #pragma unroll
            for (int reg = 0; reg < 4; reg++)
                acc[rt][ct][reg] = fmaxf(acc[rt][ct][reg] + b1v[ct], 0.f);

    #pragma unroll
    for (int rt = 0; rt < 4; rt++) {
        #pragma unroll
        for (int reg = 0; reg < 4; reg++) {
            float s = 0.f, q = 0.f;
            #pragma unroll
            for (int ct = 0; ct < 8; ct++) { float f = acc[rt][ct][reg]; s += f; q = fmaf(f, f, q); }
            #pragma unroll
            for (int m = 1; m <= 8; m <<= 1) { s += __shfl_xor(s, m); q += __shfl_xor(q, m); }
            if (ln == 0) {
                int row = rt * 16 + quad * 4 + reg;
                rowsum[row][w] = s; rowsq[row][w] = q;
            }
        }
    }
    __syncthreads();
    if (tid < 64) {
        float s = 0.f, q = 0.f;
        #pragma unroll
        for (int ww = 0; ww < 8; ww++) { s += rowsum[tid][ww]; q += rowsq[tid][ww]; }
        float mean = s * (1.f / CD);
        float var  = q * (1.f / CD) - mean * mean;
        mu2[tid] = mean; rs2[tid] = rsqrtf(var + LNEPS);
    }

    float vv[6][8];
    #pragma unroll
    for (int j = 0; j < 6; j++)
        #pragma unroll
        for (int ct = 0; ct < 8; ct++)
            vv[j][ct] = Vlds[j * CD + colc[ct]];
    #pragma unroll
    for (int rt = 0; rt < 4; rt++) {
        #pragma unroll
        for (int reg = 0; reg < 4; reg++) {
            float p0 = 0.f, p1 = 0.f, p2 = 0.f, p3 = 0.f, p4 = 0.f, p5 = 0.f;
            #pragma unroll
            for (int ct = 0; ct < 8; ct++) {
                float f = acc[rt][ct][reg];
                p0 = fmaf(f, vv[0][ct], p0); p1 = fmaf(f, vv[1][ct], p1);
                p2 = fmaf(f, vv[2][ct], p2); p3 = fmaf(f, vv[3][ct], p3);
                p4 = fmaf(f, vv[4][ct], p4); p5 = fmaf(f, vv[5][ct], p5);
            }
            #pragma unroll
            for (int m = 1; m <= 8; m <<= 1) {
                p0 += __shfl_xor(p0, m); p1 += __shfl_xor(p1, m); p2 += __shfl_xor(p2, m);
                p3 += __shfl_xor(p3, m); p4 += __shfl_xor(p4, m); p5 += __shfl_xor(p5, m);
            }
            if (ln == 0) {
                int row = rt * 16 + quad * 4 + reg;
                Sbuf[row][0][w] = p0; Sbuf[row][1][w] = p1; Sbuf[row][2][w] = p2;
                Sbuf[row][3][w] = p3; Sbuf[row][4][w] = p4; Sbuf[row][5][w] = p5;
            }
        }
    }
    __syncthreads();

    if (tid < 384) {
        int r = tid / 6, j = tid - r * 6;
        float S = 0.f;
        #pragma unroll
        for (int ww = 0; ww < 8; ww++) S += Sbuf[r][j][ww];
        int gr = row0 + r;
        float cs = 0.f;
        #pragma unroll
        for (int jj = 0; jj < 6; jj++) cs += credit[(size_t)gr * 6 + jj];
        float bias = (cs > 0.f) ? credit[(size_t)gr * 6 + j] / cs : (1.f / 6.f);
        out[(size_t)gr * 6 + j] = rs2[r] * S - mu2[r] * rs2[r] * c1L[j] + c0L[j] + bias;
    }
}

extern "C" void kernel_launch(void* const* d_in, const int* in_sizes, int n_in,
                              void* d_out, int out_size, void* d_ws, size_t ws_size,
                              hipStream_t stream) {
    const float* encode     = (const float*)d_in[0];
    const float* credit     = (const float*)d_in[1];
    const float* meta_table = (const float*)d_in[2];
    const float* conv_w     = (const float*)d_in[3];
    const float* conv_b     = (const float*)d_in[4];
    const float* ln1_g      = (const float*)d_in[5];
    const float* ln1_b      = (const float*)d_in[6];
    const float* mlp1_w     = (const float*)d_in[7];
    const float* mlp1_b     = (const float*)d_in[8];
    const float* ln2_g      = (const float*)d_in[9];
    const float* ln2_b      = (const float*)d_in[10];
    const float* out_w      = (const float*)d_in[11];
    const float* out_b      = (const float*)d_in[12];
    const int*   meta_ids   = (const int*)d_in[13];
    const int*   cat_ids    = (const int*)d_in[14];
    const int*   cat_seg    = (const int*)d_in[15];
    float* out = (float*)d_out;

    // ws layout: w1b (g-folded bf16) | G | B0 | c0 | c1
    const size_t OFF_G  = (size_t)CD * KPAD * sizeof(unsigned short);   // 1,114,112
    const size_t OFF_B0 = OFF_G + CD * sizeof(float);
    const size_t OFF_C0 = OFF_B0 + CD * sizeof(float);
    const size_t OFF_C1 = OFF_C0 + 32;
    const size_t WS_NEED = OFF_C1 + 32;                                 // 1,122,432

    if (ws_size >= WS_NEED) {
        char* ws = (char*)d_ws;
        unsigned short* w1b = (unsigned short*)ws;
        float* G  = (float*)(ws + OFF_G);
        float* B0 = (float*)(ws + OFF_B0);
        float* c0 = (float*)(ws + OFF_C0);
        float* c1 = (float*)(ws + OFF_C1);
        k_prep<<<PREP_BLKS, 256, 0, stream>>>(mlp1_w, ln1_g, ln1_b, ln2_g, ln2_b, out_w, out_b,
                                              w1b, G, B0, c0, c1);
        k_mainw<<<BSZ / BM, 512, 0, stream>>>(
            encode, credit, meta_table, conv_w, conv_b,
            w1b, mlp1_b, ln2_g, out_w, G, B0, c0, c1,
            meta_ids, cat_ids, cat_seg, out);
    } else {
        k_legacy<<<BSZ / 64, 512, 0, stream>>>(
            encode, credit, meta_table, conv_w, conv_b, ln1_g, ln1_b,
            mlp1_w, mlp1_b, ln2_g, ln2_b, out_w, out_b,
            meta_ids, cat_ids, cat_seg, out);
    }
}

// Round 13
// 197.879 us; speedup vs baseline: 1.8470x; 1.1472x over previous
//
#include <hip/hip_runtime.h>

#define BSZ   32768
#define H     512
#define K1DIM 532      // H + 20
#define KPAD  544      // padded to multiple of 32 (ws path)
#define ASTR  552      // LDS A row stride in shorts (2-way bank aliasing only)
#define BM    128      // rows per block (R7 evidence: BM=64/2-blocks regressed timed +8.7%)
#define CD    1024
#define NCATS 262144
#define LNEPS 1e-6f
#define PREP_BLKS 128  // R12-verified: fence cost scales with wave count (R11: 9732 waves = 167us)

typedef short bf16x8 __attribute__((ext_vector_type(8)));   // 8 bf16 in 4 VGPRs
typedef float f32x4  __attribute__((ext_vector_type(4)));

__device__ __forceinline__ unsigned short f2bf(float x) {
    unsigned int u = __float_as_uint(x);
    u += 0x7FFFu + ((u >> 16) & 1u);        // RNE
    return (unsigned short)(u >> 16);
}

__device__ __forceinline__ unsigned int pack_bf2(float lo, float hi) {
    return __builtin_amdgcn_perm(__float_as_uint(hi), __float_as_uint(lo), 0x07060302u);
}

// sum over 16 contiguous lanes via DPP only; full sum valid on ln==15 (R6-verified)
__device__ __forceinline__ float dpp_red16(float x) {
    x += __int_as_float(__builtin_amdgcn_update_dpp(0, __float_as_int(x), 0xB1, 0xf, 0xf, true)); // quad_perm [1,0,3,2]
    x += __int_as_float(__builtin_amdgcn_update_dpp(0, __float_as_int(x), 0x4E, 0xf, 0xf, true)); // quad_perm [2,3,0,1]
    x += __int_as_float(__builtin_amdgcn_update_dpp(0, __float_as_int(x), 0x114, 0xf, 0xf, true)); // row_shr:4
    x += __int_as_float(__builtin_amdgcn_update_dpp(0, __float_as_int(x), 0x118, 0xf, 0xf, true)); // row_shr:8
    return x;
}

// p-ary lower_bound over sorted cat_seg: 3 rounds of 64 probes (one wave) — R6-verified
__device__ __forceinline__ int psearch64(const int* __restrict__ seg, int target) {
    int lane = threadIdx.x & 63;
    int lo = 0, step = 4096;
    #pragma unroll
    for (int lvl = 0; lvl < 3; ++lvl) {
        int idx = lo + lane * step;
        bool lt = (idx < NCATS) && (seg[idx < NCATS ? idx : NCATS - 1] < target);
        unsigned long long m = __ballot(lt);
        int c = __popcll(m);
        if (c > 0) lo = lo + (c - 1) * step + 1;
        step >>= 6;
    }
    return lo;
}

// ---------- merged prep: w1 fold+convert | G/B0 columns | c0/c1 ----------
// R11/R12-verified: release fence cost ~0.14us/wave serialized per XCD. R13: demote
// to ONE fence wave per block — the L2 writeback is physically XCD-wide, so wave 0's
// fence (after __syncthreads drains all the block's stores into write-through L1->L2)
// covers every store the block made. Each block fences its own XCD.
__global__ void k_prep(const float* __restrict__ w1f, const float* __restrict__ ln1_g,
                       const float* __restrict__ ln1_b, const float* __restrict__ ln2_g,
                       const float* __restrict__ ln2_b, const float* __restrict__ out_w,
                       const float* __restrict__ out_b,
                       unsigned short* __restrict__ w1b, float* __restrict__ G,
                       float* __restrict__ B0, float* __restrict__ c0, float* __restrict__ c1) {
    const int bid = blockIdx.x, tid = threadIdx.x;
    const int lane = tid & 63, w = tid >> 6;

    // w1b fold+convert: grid-stride over CD*KPAD = 557056 (17 iters/thread)
    for (int idx = bid * 256 + tid; idx < CD * KPAD; idx += PREP_BLKS * 256) {
        int row = idx / KPAD, k = idx - row * KPAD;
        float v = (k < K1DIM) ? w1f[(size_t)row * K1DIM + k] * ln1_g[k] : 0.f;  // fold ln1_g
        w1b[idx] = f2bf(v);
    }

    // G/B0: 8 cols per block (2 per wave); 128*8 = 1024 = CD
    #pragma unroll
    for (int c = 0; c < 2; ++c) {
        int col = bid * 8 + w * 2 + c;
        float g = 0.f, b = 0.f;
        for (int k = lane; k < K1DIM; k += 64) {
            float wv = w1f[(size_t)col * K1DIM + k];
            g = fmaf(ln1_g[k], wv, g);
            b = fmaf(ln1_b[k], wv, b);
        }
        #pragma unroll
        for (int m = 1; m < 64; m <<= 1) { g += __shfl_xor(g, m); b += __shfl_xor(b, m); }
        if (lane == 0) { G[col] = g; B0[col] = b; }
    }

    // c0/c1: blocks 0..5, wave 0 (j = bid)
    if (bid < 6 && w == 0) {
        int j = bid;
        float s1 = 0.f, s0 = 0.f;
        for (int c = lane; c < CD; c += 64) {
            float wv = out_w[j * CD + c];
            s1 = fmaf(ln2_g[c], wv, s1);
            s0 = fmaf(ln2_b[c], wv, s0);
        }
        #pragma unroll
        for (int m = 1; m < 64; m <<= 1) { s1 += __shfl_xor(s1, m); s0 += __shfl_xor(s0, m); }
        if (lane == 0) { c1[j] = s1; c0[j] = s0 + out_b[j]; }
    }

    __syncthreads();                 // drain all block stores (vmcnt) before writeback
    if (tid < 64) __threadfence();   // RELEASE: one wave writes back the XCD L2
}

// ================= ws-path fused kernel: BM=128, 1 block/CU, 2 waves/SIMD =================
// R11-verified correct; R13: acquire fence demoted to one wave per block (invalidate is
// CU-L1/XCD-L2-wide), followed by __syncthreads so all waves' ws reads (c0p/c1p in
// Phase A, w1b in GEMM) are ordered after the invalidate.
__global__ __launch_bounds__(512, 2) void k_mainw(
    const float* __restrict__ encode, const float* __restrict__ credit,
    const float* __restrict__ meta_table, const float* __restrict__ conv_w,
    const float* __restrict__ conv_b,
    const unsigned short* __restrict__ w1b, const float* __restrict__ b1,
    const float* __restrict__ ln2_g, const float* __restrict__ out_w,
    const float* __restrict__ Gc, const float* __restrict__ B0c,
    const float* __restrict__ c0p, const float* __restrict__ c1p,
    const int* __restrict__ meta_ids, const int* __restrict__ cat_ids,
    const int* __restrict__ cat_seg, float* __restrict__ out)
{
    __shared__ unsigned short Alds[BM * ASTR];   // 141312 B (raw bf16 x; ln1_g folded into W)
    __shared__ float Ssum[BM][10];               // 5120 B  [row][s,q,p0..5,pad,pad] — atomic acc
    __shared__ float cwL[90], cbL[5];
    __shared__ float sEnc[BM], qEnc[BM];         // stats, then overwritten with mu/rs
    __shared__ float mu2[BM], rs2[BM];
    __shared__ float c0L[6], c1L[6];
    __shared__ int   startsL[BM + 1];
    __shared__ int   sLoL, sHiL;

    const int tid  = threadIdx.x;
    const int row0 = blockIdx.x * BM;
    const int lane = tid & 63;
    const int w    = tid >> 6;

    if (tid < 64) __threadfence();   // ACQUIRE: one wave invalidates CU L1 + XCD L2
    __syncthreads();                 // all ws reads below ordered after the invalidate

    // ---- Phase A: p-ary boundary searches (waves 0,1) || constants (rest) + zero Ssum
    if (w == 0) {
        int L = psearch64(cat_seg, row0);
        if (lane == 0) sLoL = L;
    } else if (w == 1) {
        int L = psearch64(cat_seg, row0 + BM);
        if (lane == 0) sHiL = L;
    } else {
        const int t = tid - 128;
        if (t < 90) cwL[t] = conv_w[t];
        else if (t < 95) cbL[t - 90] = conv_b[t - 90];
        else if (t < 101) c0L[t - 95] = c0p[t - 95];
        else if (t < 107) c1L[t - 101] = c1p[t - 101];
    }
    for (int i = tid; i < BM * 10; i += 512) ((float*)Ssum)[i] = 0.f;
    __syncthreads();

    // ---- Phase B: boundary scan + encode staging/stats (two 64-row halves, 8 lanes/row)
    {
        const int slo = sLoL, shi = sHiL;
        for (int i = slo - 1 + tid; i < shi; i += 512) {
            int a = (i >= 0) ? cat_seg[i] : -1;
            int b = (i + 1 < NCATS) ? cat_seg[i + 1] : BSZ;
            int rlo = max(a + 1, row0);
            int rhi = min(b, row0 + BM);
            for (int r = rlo; r <= rhi; ++r) startsL[r - row0] = i + 1;
        }
    }
    #pragma unroll
    for (int rr = 0; rr < 2; ++rr) {
        const int r  = (tid >> 3) + rr * 64;
        const int cl = tid & 7;
        const float* erow = encode + (size_t)(row0 + r) * H;
        unsigned short* arow = Alds + r * ASTR;
        float s = 0.f, q = 0.f;
        #pragma unroll 4
        for (int i = 0; i < 16; i++) {
            int col = cl * 4 + i * 32;
            const float4 v = *(const float4*)(erow + col);
            s += v.x + v.y + v.z + v.w;
            q += v.x*v.x + v.y*v.y + v.z*v.z + v.w*v.w;
            ushort4 st = { f2bf(v.x), f2bf(v.y), f2bf(v.z), f2bf(v.w) };
            *(ushort4*)(arow + col) = st;
        }
        #pragma unroll
        for (int m = 1; m <= 4; m <<= 1) { s += __shfl_xor(s, m); q += __shfl_xor(q, m); }
        if (cl == 0) { sEnc[r] = s; qEnc[r] = q; }
    }
    __syncthreads();

    // ---- Phase C: meta gather + conv via in-wave shuffles (two 64-row halves)
    #pragma unroll 1
    for (int rr = 0; rr < 2; ++rr) {
        const int r = (tid >> 3) + rr * 64, k = tid & 7;
        const int s = startsL[r], e = startsL[r + 1];
        float val[8];
        #pragma unroll
        for (int d = 0; d < 8; d++) val[d] = 0.f;
        for (int i = s + k; i < e; i += 8) {
            int id = cat_ids[i];
            const float4 a = *(const float4*)(meta_table + (size_t)id * 8);
            const float4 b = *(const float4*)(meta_table + (size_t)id * 8 + 4);
            val[0] += a.x; val[1] += a.y; val[2] += a.z; val[3] += a.w;
            val[4] += b.x; val[5] += b.y; val[6] += b.z; val[7] += b.w;
        }
        #pragma unroll
        for (int m = 1; m <= 4; m <<= 1)
            #pragma unroll
            for (int d = 0; d < 8; d++) val[d] += __shfl_xor(val[d], m);
        float inv = 1.f / fmaxf((float)(e - s), 1.f);
        if (k == 0) {
            #pragma unroll
            for (int d = 0; d < 8; d++) val[d] *= inv;      // lane 0: avg_cat
        } else if (k <= 5) {
            int id = meta_ids[(size_t)(row0 + r) * 5 + (k - 1)];
            const float4 a = *(const float4*)(meta_table + (size_t)id * 8);
            const float4 b = *(const float4*)(meta_table + (size_t)id * 8 + 4);
            val[0] = a.x; val[1] = a.y; val[2] = a.z; val[3] = a.w;
            val[4] = b.x; val[5] = b.y; val[6] = b.z; val[7] = b.w;
        }
        const int base = lane & 56;
        float mm[6][8];
        #pragma unroll
        for (int src = 0; src < 6; src++)
            #pragma unroll
            for (int d = 0; d < 8; d++)
                mm[src][d] = __shfl(val[d], base + src);
        unsigned short* arow = Alds + r * ASTR;
        float s2 = 0.f, q2 = 0.f;
        if (k < 5) {                        // lane k computes conv output channel oc=k
            const int oc = k;
            float c[6];
            #pragma unroll
            for (int x = 0; x < 6; x++) {
                float a = cbL[oc];
                #pragma unroll
                for (int ic = 0; ic < 6; ic++)
                    #pragma unroll
                    for (int kj = 0; kj < 3; kj++)
                        a = fmaf(mm[ic][x + kj], cwL[(oc * 6 + ic) * 3 + kj], a);
                c[x] = fmaxf(a, 0.f);
            }
            unsigned short o[4];
            #pragma unroll
            for (int x = 0; x < 4; x++) {
                float p = fmaxf(fmaxf(c[x], c[x + 1]), c[x + 2]);
                s2 += p; q2 = fmaf(p, p, q2);
                o[x] = f2bf(p);
            }
            ushort4 st = { o[0], o[1], o[2], o[3] };
            *(ushort4*)(arow + 512 + oc * 4) = st;
        } else {                            // lanes 5,6,7: zero the K-pad cols 532..543
            ushort4 z = { 0, 0, 0, 0 };
            *(ushort4*)(arow + 532 + (k - 5) * 4) = z;
        }
        #pragma unroll
        for (int m = 1; m <= 4; m <<= 1) { s2 += __shfl_xor(s2, m); q2 += __shfl_xor(q2, m); }
        if (k == 0) { sEnc[r] += s2; qEnc[r] += q2; }
    }
    __syncthreads();
    if (tid < BM) {                         // finalize LN1 stats in place: sEnc<-mu, qEnc<-rs
        float mean = sEnc[tid] * (1.f / K1DIM);
        float var  = qEnc[tid] * (1.f / K1DIM) - mean * mean;
        sEnc[tid] = mean;
        qEnc[tid] = rsqrtf(var + LNEPS);
    }
    __syncthreads();

    // ---- GEMM1: two 64-col passes per wave, acc[8][4]=128 AGPR; depth-2 A/B prefetch
    const int ln   = lane & 15;
    const int quad = lane >> 4;
    const unsigned short* aBase = Alds + ln * ASTR + quad * 8;

#define LDA8(A, kk) { _Pragma("unroll") for (int rt = 0; rt < 8; rt++) \
        A[rt] = *(const bf16x8*)(aBase + rt * 16 * ASTR + (kk) * 32); }
#define LDB4(Bv, kk) { _Pragma("unroll") for (int ct = 0; ct < 4; ct++) \
        Bv[ct] = *(const bf16x8*)(bp0 + (size_t)ct * 16 * KPAD + (kk) * 32); }
#define MFM(A, Bv) { _Pragma("unroll") for (int ct = 0; ct < 4; ct++) \
        _Pragma("unroll") for (int rt = 0; rt < 8; rt++) \
        acc[rt][ct] = __builtin_amdgcn_mfma_f32_16x16x32_bf16(A[rt], Bv[ct], acc[rt][ct], 0, 0, 0); }

    #pragma unroll 1
    for (int pass = 0; pass < 2; ++pass) {
        const int cb = pass * 512 + w * 64;
        const unsigned short* bp0 = w1b + (size_t)(cb + ln) * KPAD + quad * 8;

        f32x4 acc[8][4];
        #pragma unroll
        for (int rt = 0; rt < 8; rt++)
            #pragma unroll
            for (int ct = 0; ct < 4; ct++)
                acc[rt][ct] = f32x4{0.f, 0.f, 0.f, 0.f};

        bf16x8 bP[4], bQ[4], aF[8], aG[8];
        LDB4(bP, 0)
        LDB4(bQ, 1)
        #pragma unroll 1
        for (int kk = 0; kk < 16; kk += 2) {
            LDA8(aF, kk)
            MFM(aF, bP)
            LDB4(bP, kk + 2)                     // kk+2 <= 16: always valid
            LDA8(aG, kk + 1)
            MFM(aG, bQ)
            int k3 = (kk + 3 <= 16) ? kk + 3 : 1;
            LDB4(bQ, k3)
        }
        LDA8(aF, 16)
        MFM(aF, bP)

        // epilogue: h = relu(rs*(acc - mu*G) + B0 + b1); DPP-reduce; LDS atomic accumulate
        int colc[4]; float Gv[4], Bv[4], bv[4], vv[6][4];
        #pragma unroll
        for (int ct = 0; ct < 4; ct++) {
            colc[ct] = cb + ct * 16 + ln;
            Gv[ct] = Gc[colc[ct]]; Bv[ct] = B0c[colc[ct]]; bv[ct] = b1[colc[ct]];
            float g2 = ln2_g[colc[ct]];
            #pragma unroll
            for (int j = 0; j < 6; j++) vv[j][ct] = g2 * out_w[j * CD + colc[ct]];
        }
        #pragma unroll
        for (int rt = 0; rt < 8; rt++) {
            #pragma unroll
            for (int reg = 0; reg < 4; reg++) {
                const int row = rt * 16 + quad * 4 + reg;
                const float mu = sEnc[row], rs = qEnc[row];
                float s = 0.f, q = 0.f, p[6];
                #pragma unroll
                for (int j = 0; j < 6; j++) p[j] = 0.f;
                #pragma unroll
                for (int ct = 0; ct < 4; ct++) {
                    float h = fmaxf(rs * (acc[rt][ct][reg] - mu * Gv[ct]) + Bv[ct] + bv[ct], 0.f);
                    s += h; q = fmaf(h, h, q);
                    #pragma unroll
                    for (int j = 0; j < 6; j++) p[j] = fmaf(h, vv[j][ct], p[j]);
                }
                s = dpp_red16(s); q = dpp_red16(q);
                #pragma unroll
                for (int j = 0; j < 6; j++) p[j] = dpp_red16(p[j]);
                if (ln == 15) {                  // full 16-lane sum lives on ln==15 (R6-verified)
                    atomicAdd(&Ssum[row][0], s);
                    atomicAdd(&Ssum[row][1], q);
                    #pragma unroll
                    for (int j = 0; j < 6; j++) atomicAdd(&Ssum[row][2 + j], p[j]);
                }
            }
        }
    }
#undef LDA8
#undef LDB4
#undef MFM
    __syncthreads();

    if (tid < BM) {
        float s = Ssum[tid][0], q = Ssum[tid][1];
        float mean = s * (1.f / CD);
        float var  = q * (1.f / CD) - mean * mean;
        mu2[tid] = mean; rs2[tid] = rsqrtf(var + LNEPS);
    }
    __syncthreads();

    for (int t = tid; t < BM * 6; t += 512) {
        int r = t / 6, j = t - r * 6;
        float S = Ssum[r][2 + j];
        int gr = row0 + r;
        float cs = 0.f;
        #pragma unroll
        for (int jj = 0; jj < 6; jj++) cs += credit[(size_t)gr * 6 + jj];
        float bias = (cs > 0.f) ? credit[(size_t)gr * 6 + j] / cs : (1.f / 6.f);
        out[(size_t)gr * 6 + j] = rs2[r] * S - mu2[r] * rs2[r] * c1L[j] + c0L[j] + bias;
    }
}

// ================= legacy fallback (no workspace) — R3-verified (BM=64) =================
__global__ __launch_bounds__(512, 2) void k_legacy(
    const float* __restrict__ encode, const float* __restrict__ credit,
    const float* __restrict__ meta_table, const float* __restrict__ conv_w,
    const float* __restrict__ conv_b, const float* __restrict__ ln1_g,
    const float* __restrict__ ln1_b, const float* __restrict__ w1f,
    const float* __restrict__ b1,
    const float* __restrict__ ln2_g, const float* __restrict__ ln2_b,
    const float* __restrict__ out_w, const float* __restrict__ out_b,
    const int* __restrict__ meta_ids, const int* __restrict__ cat_ids,
    const int* __restrict__ cat_seg, float* __restrict__ out)
{
    __shared__ unsigned short Alds[64 * ASTR];
    __shared__ float Vlds[6 * CD];
    __shared__ float gL[K1DIM], bL[K1DIM];
    __shared__ float cwL[90], cbL[5];
    __shared__ float mfL[64][20];
    __shared__ float sEnc[64], qEnc[64];
    __shared__ float muL[64], rsL[64];
    __shared__ float rowsum[64][8], rowsq[64][8];
    __shared__ float mu2[64], rs2[64];
    __shared__ float Sbuf[64][6][8];
    __shared__ float c0L[6], c1L[6];
    __shared__ int   startsL[65];
    __shared__ int   sLoL, sHiL;

    const int tid  = threadIdx.x;
    const int row0 = blockIdx.x * 64;
    const int lane = tid & 63;
    const int w    = tid >> 6;

    if (w == 0) {
        if (lane < 2) {
            int target = row0 + lane * 64;
            int lo = 0, hi = NCATS;
            while (lo < hi) { int mid = (lo + hi) >> 1; if (cat_seg[mid] < target) lo = mid + 1; else hi = mid; }
            if (lane == 0) sLoL = lo; else sHiL = lo;
        }
    } else {
        const int t = tid - 64;
        for (int i = t; i < 6 * CD; i += 448) Vlds[i] = ln2_g[i & (CD - 1)] * out_w[i];
        for (int i = t; i < K1DIM; i += 448) { gL[i] = ln1_g[i]; bL[i] = ln1_b[i]; }
        if (t < 90) cwL[t] = conv_w[t];
        if (t < 5)  cbL[t] = conv_b[t];
        for (int r = w - 1; r < 64; r += 7) {
            const float* p = encode + (size_t)(row0 + r) * H + lane * 8;
            float4 v0 = *(const float4*)p;
            float4 v1 = *(const float4*)(p + 4);
            float s = v0.x + v0.y + v0.z + v0.w + v1.x + v1.y + v1.z + v1.w;
            float q = v0.x*v0.x + v0.y*v0.y + v0.z*v0.z + v0.w*v0.w
                    + v1.x*v1.x + v1.y*v1.y + v1.z*v1.z + v1.w*v1.w;
            for (int m = 1; m < 64; m <<= 1) { s += __shfl_xor(s, m); q += __shfl_xor(q, m); }
            if (lane == 0) { sEnc[r] = s; qEnc[r] = q; }
        }
    }
    __syncthreads();

    {
        const int slo = sLoL, shi = sHiL;
        for (int i = slo - 1 + tid; i < shi; i += 512) {
            int a = (i >= 0) ? cat_seg[i] : -1;
            int b = (i + 1 < NCATS) ? cat_seg[i + 1] : BSZ;
            int rlo = max(a + 1, row0);
            int rhi = min(b, row0 + 64);
            for (int r = rlo; r <= rhi; ++r) startsL[r - row0] = i + 1;
        }
    }
    if (w >= 1 && w <= 6) {
        int j = w - 1;
        float s1 = 0.f, s0 = 0.f;
        for (int c = lane; c < CD; c += 64) {
            s1 += Vlds[j * CD + c];
            s0 = fmaf(ln2_b[c], out_w[j * CD + c], s0);
        }
        for (int m = 1; m < 64; m <<= 1) { s1 += __shfl_xor(s1, m); s0 += __shfl_xor(s0, m); }
        if (lane == 0) { c1L[j] = s1; c0L[j] = s0 + out_b[j]; }
    }
    __syncthreads();

    if (tid < 64) {
        const int r = tid;
        const int s = startsL[r], e = startsL[r + 1];
        float mm[6][8];
        float sum[8];
        #pragma unroll
        for (int d = 0; d < 8; d++) sum[d] = 0.f;
        for (int i = s; i < e; i++) {
            int id = cat_ids[i];
            const float4 a = *(const float4*)(meta_table + (size_t)id * 8);
            const float4 b = *(const float4*)(meta_table + (size_t)id * 8 + 4);
            sum[0] += a.x; sum[1] += a.y; sum[2] += a.z; sum[3] += a.w;
            sum[4] += b.x; sum[5] += b.y; sum[6] += b.z; sum[7] += b.w;
        }
        float cnt = fmaxf((float)(e - s), 1.f);
        #pragma unroll
        for (int d = 0; d < 8; d++) mm[0][d] = sum[d] / cnt;
        #pragma unroll
        for (int i = 0; i < 5; i++) {
            int id = meta_ids[(size_t)(row0 + r) * 5 + i];
            const float4 a = *(const float4*)(meta_table + (size_t)id * 8);
            const float4 b = *(const float4*)(meta_table + (size_t)id * 8 + 4);
            mm[1+i][0] = a.x; mm[1+i][1] = a.y; mm[1+i][2] = a.z; mm[1+i][3] = a.w;
            mm[1+i][4] = b.x; mm[1+i][5] = b.y; mm[1+i][6] = b.z; mm[1+i][7] = b.w;
        }
        float mfv[20];
        #pragma unroll
        for (int oc = 0; oc < 5; oc++) {
            float c[6];
            #pragma unroll
            for (int x = 0; x < 6; x++) {
                float a = cbL[oc];
                #pragma unroll
                for (int ic = 0; ic < 6; ic++)
                    #pragma unroll
                    for (int k = 0; k < 3; k++)
                        a = fmaf(mm[ic][x + k], cwL[(oc * 6 + ic) * 3 + k], a);
                c[x] = fmaxf(a, 0.f);
            }
            #pragma unroll
            for (int x = 0; x < 4; x++)
                mfv[oc * 4 + x] = fmaxf(fmaxf(c[x], c[x + 1]), c[x + 2]);
        }
        float sT = sEnc[r], qT = qEnc[r];
        #pragma unroll
        for (int j = 0; j < 20; j++) {
            mfL[r][j] = mfv[j];
            sT += mfv[j]; qT = fmaf(mfv[j], mfv[j], qT);
        }
        float mean = sT * (1.f / K1DIM);
        float var  = qT * (1.f / K1DIM) - mean * mean;
        muL[r] = mean;
        rsL[r] = rsqrtf(var + LNEPS);
    }
    __syncthreads();

    for (int i = tid; i < 64 * 136; i += 512) {
        int r = i / 136, c4 = i - r * 136;
        int col = c4 * 4;
        unsigned short o0 = 0, o1 = 0, o2 = 0, o3 = 0;
        if (c4 < 133) {
            float x0, x1, x2, x3;
            if (c4 < 128) {
                const float4 v = *(const float4*)&encode[(size_t)(row0 + r) * H + col];
                x0 = v.x; x1 = v.y; x2 = v.z; x3 = v.w;
            } else {
                int o = col - H;
                x0 = mfL[r][o]; x1 = mfL[r][o + 1]; x2 = mfL[r][o + 2]; x3 = mfL[r][o + 3];
            }
            float m = muL[r], rr = rsL[r];
            o0 = f2bf((x0 - m) * rr * gL[col + 0] + bL[col + 0]);
            o1 = f2bf((x1 - m) * rr * gL[col + 1] + bL[col + 1]);
            o2 = f2bf((x2 - m) * rr * gL[col + 2] + bL[col + 2]);
            o3 = f2bf((x3 - m) * rr * gL[col + 3] + bL[col + 3]);
        }
        ushort4 st = { o0, o1, o2, o3 };
        *(ushort4*)&Alds[r * ASTR + col] = st;
    }
    __syncthreads();

    const int ln   = lane & 15;
    const int quad = lane >> 4;
    const int cb   = w * 128;

    f32x4 acc[4][8];
    #pragma unroll
    for (int rt = 0; rt < 4; rt++)
        #pragma unroll
        for (int ct = 0; ct < 8; ct++)
            acc[rt][ct] = f32x4{0.f, 0.f, 0.f, 0.f};

    #pragma unroll 1
    for (int kk = 0; kk < 16; kk++) {
        bf16x8 af[4];
        #pragma unroll
        for (int rt = 0; rt < 4; rt++)
            af[rt] = *(const bf16x8*)&Alds[(rt * 16 + ln) * ASTR + kk * 32 + quad * 8];
        #pragma unroll
        for (int ct = 0; ct < 8; ct++) {
            const float* wrow = w1f + (size_t)(cb + ct * 16 + ln) * K1DIM + kk * 32 + quad * 8;
            const float4 fa = *(const float4*)wrow;
            const float4 fb = *(const float4*)(wrow + 4);
            union { bf16x8 v; unsigned int u[4]; } bu;
            bu.u[0] = pack_bf2(fa.x, fa.y);
            bu.u[1] = pack_bf2(fa.z, fa.w);
            bu.u[2] = pack_bf2(fb.x, fb.y);
            bu.u[3] = pack_bf2(fb.z, fb.w);
            #pragma unroll
            for (int rt = 0; rt < 4; rt++)
                acc[rt][ct] = __builtin_amdgcn_mfma_f32_16x16x32_bf16(af[rt], bu.v, acc[rt][ct], 0, 0, 0);
        }
    }
    {
        bf16x8 af[4];
        #pragma unroll
        for (int rt = 0; rt < 4; rt++)
            af[rt] = *(const bf16x8*)&Alds[(rt * 16 + ln) * ASTR + 512 + quad * 8];
        #pragma unroll
        for (int ct = 0; ct < 8; ct++) {
            union { bf16x8 v; unsigned int u[4]; } bu;
            bu.u[0] = 0; bu.u[1] = 0; bu.u[2] = 0; bu.u[3] = 0;
            const float* wrow = w1f + (size_t)(cb + ct * 16 + ln) * K1DIM + 512 + quad * 8;
            if (quad < 2) {
                const float4 fa = *(const float4*)wrow;
                const float4 fb = *(const float4*)(wrow + 4);
                bu.u[0] = pack_bf2(fa.x, fa.y);
                bu.u[1] = pack_bf2(fa.z, fa.w);
                bu.u[2] = pack_bf2(fb.x, fb.y);
                bu.u[3] = pack_bf2(fb.z, fb.w);
            } else if (quad == 2) {
                const float4 fa = *(const float4*)wrow;
                bu.u[0] = pack_bf2(fa.x, fa.y);
                bu.u[1] = pack_bf2(fa.z, fa.w);
            }
            #pragma unroll
            for (int rt = 0; rt < 4; rt++)
                acc[rt][ct] = __builtin_amdgcn_mfma_f32_16x16x32_bf16(af[rt], bu.v, acc[rt][ct], 0, 0, 0);
        }
    }

    float b1v[8]; int colc[8];
    #pragma unroll
    for (int ct = 0; ct < 8; ct++) { colc[ct] = cb + ct * 16 + ln; b1v[ct] = b1[colc[ct]]; }
    #pragma unroll
    for (int rt = 0; rt < 4; rt++)
        #pragma unroll
        for (int ct = 0; ct < 8; ct++)
            #pragma unroll
            for (int reg = 0; reg < 4; reg++)
                acc[rt][ct][reg] = fmaxf(acc[rt][ct][reg] + b1v[ct], 0.f);

    #pragma unroll
    for (int rt = 0; rt < 4; rt++) {
        #pragma unroll
        for (int reg = 0; reg < 4; reg++) {
            float s = 0.f, q = 0.f;
            #pragma unroll
            for (int ct = 0; ct < 8; ct++) { float f = acc[rt][ct][reg]; s += f; q = fmaf(f, f, q); }
            #pragma unroll
            for (int m = 1; m <= 8; m <<= 1) { s += __shfl_xor(s, m); q += __shfl_xor(q, m); }
            if (ln == 0) {
                int row = rt * 16 + quad * 4 + reg;
                rowsum[row][w] = s; rowsq[row][w] = q;
            }
        }
    }
    __syncthreads();
    if (tid < 64) {
        float s = 0.f, q = 0.f;
        #pragma unroll
        for (int ww = 0; ww < 8; ww++) { s += rowsum[tid][ww]; q += rowsq[tid][ww]; }
        float mean = s * (1.f / CD);
        float var  = q * (1.f / CD) - mean * mean;
        mu2[tid] = mean; rs2[tid] = rsqrtf(var + LNEPS);
    }

    float vv[6][8];
    #pragma unroll
    for (int j = 0; j < 6; j++)
        #pragma unroll
        for (int ct = 0; ct < 8; ct++)
            vv[j][ct] = Vlds[j * CD + colc[ct]];
    #pragma unroll
    for (int rt = 0; rt < 4; rt++) {
        #pragma unroll
        for (int reg = 0; reg < 4; reg++) {
            float p0 = 0.f, p1 = 0.f, p2 = 0.f, p3 = 0.f, p4 = 0.f, p5 = 0.f;
            #pragma unroll
            for (int ct = 0; ct < 8; ct++) {
                float f = acc[rt][ct][reg];
                p0 = fmaf(f, vv[0][ct], p0); p1 = fmaf(f, vv[1][ct], p1);
                p2 = fmaf(f, vv[2][ct], p2); p3 = fmaf(f, vv[3][ct], p3);
                p4 = fmaf(f, vv[4][ct], p4); p5 = fmaf(f, vv[5][ct], p5);
            }
            #pragma unroll
            for (int m = 1; m <= 8; m <<= 1) {
                p0 += __shfl_xor(p0, m); p1 += __shfl_xor(p1, m); p2 += __shfl_xor(p2, m);
                p3 += __shfl_xor(p3, m); p4 += __shfl_xor(p4, m); p5 += __shfl_xor(p5, m);
            }
            if (ln == 0) {
                int row = rt * 16 + quad * 4 + reg;
                Sbuf[row][0][w] = p0; Sbuf[row][1][w] = p1; Sbuf[row][2][w] = p2;
                Sbuf[row][3][w] = p3; Sbuf[row][4][w] = p4; Sbuf[row][5][w] = p5;
            }
        }
    }
    __syncthreads();

    if (tid < 384) {
        int r = tid / 6, j = tid - r * 6;
        float S = 0.f;
        #pragma unroll
        for (int ww = 0; ww < 8; ww++) S += Sbuf[r][j][ww];
        int gr = row0 + r;
        float cs = 0.f;
        #pragma unroll
        for (int jj = 0; jj < 6; jj++) cs += credit[(size_t)gr * 6 + jj];
        float bias = (cs > 0.f) ? credit[(size_t)gr * 6 + j] / cs : (1.f / 6.f);
        out[(size_t)gr * 6 + j] = rs2[r] * S - mu2[r] * rs2[r] * c1L[j] + c0L[j] + bias;
    }
}

extern "C" void kernel_launch(void* const* d_in, const int* in_sizes, int n_in,
                              void* d_out, int out_size, void* d_ws, size_t ws_size,
                              hipStream_t stream) {
    const float* encode     = (const float*)d_in[0];
    const float* credit     = (const float*)d_in[1];
    const float* meta_table = (const float*)d_in[2];
    const float* conv_w     = (const float*)d_in[3];
    const float* conv_b     = (const float*)d_in[4];
    const float* ln1_g      = (const float*)d_in[5];
    const float* ln1_b      = (const float*)d_in[6];
    const float* mlp1_w     = (const float*)d_in[7];
    const float* mlp1_b     = (const float*)d_in[8];
    const float* ln2_g      = (const float*)d_in[9];
    const float* ln2_b      = (const float*)d_in[10];
    const float* out_w      = (const float*)d_in[11];
    const float* out_b      = (const float*)d_in[12];
    const int*   meta_ids   = (const int*)d_in[13];
    const int*   cat_ids    = (const int*)d_in[14];
    const int*   cat_seg    = (const int*)d_in[15];
    float* out = (float*)d_out;

    // ws layout: w1b (g-folded bf16) | G | B0 | c0 | c1
    const size_t OFF_G  = (size_t)CD * KPAD * sizeof(unsigned short);   // 1,114,112
    const size_t OFF_B0 = OFF_G + CD * sizeof(float);
    const size_t OFF_C0 = OFF_B0 + CD * sizeof(float);
    const size_t OFF_C1 = OFF_C0 + 32;
    const size_t WS_NEED = OFF_C1 + 32;                                 // 1,122,432

    if (ws_size >= WS_NEED) {
        char* ws = (char*)d_ws;
        unsigned short* w1b = (unsigned short*)ws;
        float* G  = (float*)(ws + OFF_G);
        float* B0 = (float*)(ws + OFF_B0);
        float* c0 = (float*)(ws + OFF_C0);
        float* c1 = (float*)(ws + OFF_C1);
        k_prep<<<PREP_BLKS, 256, 0, stream>>>(mlp1_w, ln1_g, ln1_b, ln2_g, ln2_b, out_w, out_b,
                                              w1b, G, B0, c0, c1);
        k_mainw<<<BSZ / BM, 512, 0, stream>>>(
            encode, credit, meta_table, conv_w, conv_b,
            w1b, mlp1_b, ln2_g, out_w, G, B0, c0, c1,
            meta_ids, cat_ids, cat_seg, out);
    } else {
        k_legacy<<<BSZ / 64, 512, 0, stream>>>(
            encode, credit, meta_table, conv_w, conv_b, ln1_g, ln1_b,
            mlp1_w, mlp1_b, ln2_g, ln2_b, out_w, out_b,
            meta_ids, cat_ids, cat_seg, out);
    }
}